// Round 7
// baseline (368.413 us; speedup 1.0000x reference)
//
#include <hip/hip_runtime.h>
#include <math.h>

#define DIM 128
#define TPB 256
#define PREP_GRID 2048
#define SUB_CAP 32
#define SUP_CAP 64
#define OVER_MAX 65536
#define NXCD 8

// bf16 helpers: round-to-nearest-even pack, cheap unpack (hi half is a free AND)
__device__ __forceinline__ unsigned short f2bf(float f) {
    unsigned u = __float_as_uint(f);
    u += 0x7fffu + ((u >> 16) & 1u);
    return (unsigned short)(u >> 16);
}
__device__ __forceinline__ float bflo(unsigned u) { return __uint_as_float(u << 16); }
__device__ __forceinline__ float bfhi(unsigned u) { return __uint_as_float(u & 0xffff0000u); }

// compact bucket entry: (c << 14) | q, q = round(v * 16384), v in [0,1).
// Out-of-range / unusual v: quantized-clamped entry + EXACT fp32 residual edge
// routed through the overflow list -> correct for arbitrary inputs.
__device__ __forceinline__ void put_edge(int r, int c, float v, int pos, int sup,
                                         unsigned* __restrict__ pk, int cap,
                                         int* __restrict__ over_cnt, int4* __restrict__ over) {
    if (pos < cap) {
        float vc = fminf(fmaxf(v, 0.f), 16383.5f / 16384.f);
        int q = (int)fmaf(vc, 16384.f, 0.5f);
        if (q > 16383) q = 16383;
        pk[(size_t)r * cap + pos] = ((unsigned)c << 14) | (unsigned)q;
        float resid = v - (float)q * (1.f / 16384.f);   // exact: q/2^14 exact in fp32
        if (fabsf(resid) > 1.2e-4f) {                    // only out-of-range v trips this
            int op = atomicAdd(over_cnt, 1);
            if (op < OVER_MAX) over[op] = make_int4(r, c, __float_as_int(resid), sup);
        }
    } else {
        int op = atomicAdd(over_cnt, 1);
        if (op < OVER_MAX) over[op] = make_int4(r, c, __float_as_int(v), sup);
    }
}

// ================= primary path =================
// Phase split (R7): streaming (sim+diff+oa16) and binning were one kernel;
// the 153MB streaming traffic thrashed L2 and evicted partially-filled bucket
// lines early -> ~66MB of partial-sector RMW writebacks (~80us). Now separate
// kernels: bin_kernel's bucket lines stay L2-resident until full.

// prep_stream: sim partials + diff precompute (+ mode 2: old_act -> bf16).
__global__ void prep_stream_kernel(const float* __restrict__ inputs,
                                   const float* __restrict__ old_act,
                                   const int* __restrict__ fields,
                                   float* __restrict__ partials, float* __restrict__ diff,
                                   unsigned short* __restrict__ oa16,
                                   unsigned short* __restrict__ diff16, int n_old4,
                                   int mode, int n4) {
    int tid = blockIdx.x * blockDim.x + threadIdx.x;
    int stride = gridDim.x * blockDim.x;

    // sim + diff (float4 in, diff out as f32 or bf16)
    float dot = 0.f, nx = 0.f, ny = 0.f;
    for (int i = tid; i < n4; i += stride) {
        int idx = i * 4;
        int b = idx >> 7, d = idx & (DIM - 1);
        float4 x = *(const float4*)(inputs + idx);
        int f = fields[b];
        float4 y = *(const float4*)(old_act + (size_t)f * DIM + d);
        dot += x.x * y.x + x.y * y.y + x.z * y.z + x.w * y.w;
        nx  += x.x * x.x + x.y * x.y + x.z * x.z + x.w * x.w;
        ny  += y.x * y.x + y.y * y.y + y.z * y.z + y.w * y.w;
        if (mode == 2) {
            *(ushort4*)(diff16 + idx) = make_ushort4(f2bf(x.x - y.x), f2bf(x.y - y.y),
                                                     f2bf(x.z - y.z), f2bf(x.w - y.w));
        } else if (mode == 1) {
            *(float4*)(diff + idx) = make_float4(x.x - y.x, x.y - y.y, x.z - y.z, x.w - y.w);
        }
    }

    // old_act -> bf16 copy (mode 2): pure streaming
    if (mode == 2) {
        for (int i = tid; i < n_old4; i += stride) {
            int idx = i * 4;
            float4 y = *(const float4*)(old_act + idx);
            *(ushort4*)(oa16 + idx) = make_ushort4(f2bf(y.x), f2bf(y.y), f2bf(y.z), f2bf(y.w));
        }
    }

    // block-reduce sim
    for (int off = 32; off > 0; off >>= 1) {
        dot += __shfl_down(dot, off, 64);
        nx  += __shfl_down(nx,  off, 64);
        ny  += __shfl_down(ny,  off, 64);
    }
    __shared__ float s[3][4];
    int lane = threadIdx.x & 63, wv = threadIdx.x >> 6;
    if (lane == 0) { s[0][wv] = dot; s[1][wv] = nx; s[2][wv] = ny; }
    __syncthreads();
    if (threadIdx.x == 0) {
        float D = 0.f, NX = 0.f, NY = 0.f;
        for (int w = 0; w < 4; ++w) { D += s[0][w]; NX += s[1][w]; NY += s[2][w]; }
        partials[blockIdx.x * 3 + 0] = D;
        partials[blockIdx.x * 3 + 1] = NX;
        partials[blockIdx.x * 3 + 2] = NY;
    }
}

// bin_kernel: XCD-partitioned bucket binning ONLY. Group x = blocks with
// blockIdx&7==x bins rows r&7==x -> each bucket line is filled within one
// XCD's L2 (per-XCD footprint ~1.9MB < 4MB) with no competing streaming
// traffic, then written back ONCE as a full line.
__global__ void bin_kernel(const int* __restrict__ sub_rows, const int* __restrict__ sub_cols,
                           const float* __restrict__ sub_vals, int e_sub,
                           const int* __restrict__ sup_rows, const int* __restrict__ sup_cols,
                           const float* __restrict__ sup_vals, int e_sup,
                           int* __restrict__ cnt,            // [2*nrows] + over_cnt at [2*nrows]
                           unsigned* __restrict__ pk_sub, unsigned* __restrict__ pk_sup,
                           int4* __restrict__ over, int nrows) {
    int* over_cnt = cnt + 2 * nrows;
    int grp     = blockIdx.x & (NXCD - 1);
    int gblk    = blockIdx.x >> 3;
    int gtid    = gblk * blockDim.x + threadIdx.x;
    int gstride = (gridDim.x >> 3) * blockDim.x;

#define BIN_SCAN(ROWS, COLS, VALS, E, SUP, CBASE, PK, CAP)                              \
    {                                                                                   \
        int e4 = (E) & ~3;                                                              \
        for (int i = gtid * 4; i < e4; i += gstride * 4) {                              \
            int4 rr = *(const int4*)((ROWS) + i);                                       \
            bool m0 = (rr.x & (NXCD - 1)) == grp;                                       \
            bool m1 = (rr.y & (NXCD - 1)) == grp;                                       \
            bool m2 = (rr.z & (NXCD - 1)) == grp;                                       \
            bool m3 = (rr.w & (NXCD - 1)) == grp;                                       \
            int p0 = 0, p1 = 0, p2 = 0, p3 = 0;                                         \
            int c0 = 0, c1 = 0, c2 = 0, c3 = 0;                                         \
            float v0 = 0.f, v1 = 0.f, v2 = 0.f, v3 = 0.f;                               \
            if (m0) { c0 = (COLS)[i];     v0 = (VALS)[i];     p0 = atomicAdd(&cnt[(CBASE) + rr.x], 1); } \
            if (m1) { c1 = (COLS)[i + 1]; v1 = (VALS)[i + 1]; p1 = atomicAdd(&cnt[(CBASE) + rr.y], 1); } \
            if (m2) { c2 = (COLS)[i + 2]; v2 = (VALS)[i + 2]; p2 = atomicAdd(&cnt[(CBASE) + rr.z], 1); } \
            if (m3) { c3 = (COLS)[i + 3]; v3 = (VALS)[i + 3]; p3 = atomicAdd(&cnt[(CBASE) + rr.w], 1); } \
            if (m0) put_edge(rr.x, c0, v0, p0, (SUP), (PK), (CAP), over_cnt, over);     \
            if (m1) put_edge(rr.y, c1, v1, p1, (SUP), (PK), (CAP), over_cnt, over);     \
            if (m2) put_edge(rr.z, c2, v2, p2, (SUP), (PK), (CAP), over_cnt, over);     \
            if (m3) put_edge(rr.w, c3, v3, p3, (SUP), (PK), (CAP), over_cnt, over);     \
        }                                                                               \
        for (int i = e4 + gtid; i < (E); i += gstride) {                                \
            int r = (ROWS)[i];                                                          \
            if ((r & (NXCD - 1)) == grp) {                                              \
                int c = (COLS)[i]; float v = (VALS)[i];                                 \
                int p = atomicAdd(&cnt[(CBASE) + r], 1);                                \
                put_edge(r, c, v, p, (SUP), (PK), (CAP), over_cnt, over);               \
            }                                                                           \
        }                                                                               \
    }

    BIN_SCAN(sub_rows, sub_cols, sub_vals, e_sub, 0, 0,     pk_sub, SUB_CAP)
    BIN_SCAN(sup_rows, sup_cols, sup_vals, e_sup, 1, nrows, pk_sup, SUP_CAP)
#undef BIN_SCAN
}

// bf16 row accumulate: one wave per row, XCD-affine mapping.
// 16-lane quad gathers: quad q (lanes 16q..16q+15) handles edge j+q; each lane
// loads uint4 = 8 bf16 dims -> a row is 16 requests of 16B, 4 edges per
// wave-step, 16 edges in flight in the sup main loop.
__global__ void row_bucket16_kernel(const int* __restrict__ cnt,
                                    const unsigned* __restrict__ pk_sub,
                                    const unsigned* __restrict__ pk_sup,
                                    const unsigned short* __restrict__ diff16,
                                    const unsigned short* __restrict__ oa16,
                                    float* __restrict__ out, int nrows) {
    int wv = threadIdx.x >> 6, lane = threadIdx.x & 63;
    int grp = blockIdx.x & (NXCD - 1);
    int qb  = blockIdx.x >> 3;
    int r   = grp + NXCD * (qb * 4 + wv);
    if (r >= nrows) return;
    const int quad = lane >> 4;        // 0..3 : edge slot
    const int l16  = lane & 15;
    const int d8   = l16 * 8;          // dims [d8 .. d8+7]
    float a0 = 0.f, a1 = 0.f, a2 = 0.f, a3 = 0.f;
    float a4 = 0.f, a5 = 0.f, a6 = 0.f, a7 = 0.f;

#define GATH8(SRC, U)                                                       \
    {                                                                       \
        int   c_ = (int)((U) >> 14);                                        \
        float v_ = (float)((U) & 16383u) * (1.f / 16384.f);                 \
        uint4 g_ = *(const uint4*)((SRC) + ((size_t)c_ << 7) + d8);         \
        a0 += v_ * bflo(g_.x); a1 += v_ * bfhi(g_.x);                       \
        a2 += v_ * bflo(g_.y); a3 += v_ * bfhi(g_.y);                       \
        a4 += v_ * bflo(g_.z); a5 += v_ * bfhi(g_.z);                       \
        a6 += v_ * bflo(g_.w); a7 += v_ * bfhi(g_.w);                       \
    }

    // ---- sub edges (diff16) ----
    {
        int e = cnt[r]; if (e > SUB_CAP) e = SUB_CAP;
        const unsigned* bp = pk_sub + (size_t)r * SUB_CAP;
        int j = 0;
        for (; j + 8 <= e; j += 8) {
            unsigned u0 = bp[j + quad];
            unsigned u1 = bp[j + 4 + quad];
            GATH8(diff16, u0); GATH8(diff16, u1);
        }
        for (; j + 4 <= e; j += 4) {
            unsigned u0 = bp[j + quad];
            GATH8(diff16, u0);
        }
        int rem = e - j;
        if (quad < rem) {
            unsigned u0 = bp[j + quad];
            GATH8(diff16, u0);
        }
    }
    // ---- sup edges (oa16) ----
    {
        int e = cnt[nrows + r]; if (e > SUP_CAP) e = SUP_CAP;
        const unsigned* bp = pk_sup + (size_t)r * SUP_CAP;
        int j = 0;
        for (; j + 16 <= e; j += 16) {
            unsigned u0 = bp[j + quad];
            unsigned u1 = bp[j + 4 + quad];
            unsigned u2 = bp[j + 8 + quad];
            unsigned u3 = bp[j + 12 + quad];
            GATH8(oa16, u0); GATH8(oa16, u1); GATH8(oa16, u2); GATH8(oa16, u3);
        }
        for (; j + 4 <= e; j += 4) {
            unsigned u0 = bp[j + quad];
            GATH8(oa16, u0);
        }
        int rem = e - j;
        if (quad < rem) {
            unsigned u0 = bp[j + quad];
            GATH8(oa16, u0);
        }
    }
#undef GATH8
    // fold the 4 quads
    a0 += __shfl_xor(a0, 16, 64); a0 += __shfl_xor(a0, 32, 64);
    a1 += __shfl_xor(a1, 16, 64); a1 += __shfl_xor(a1, 32, 64);
    a2 += __shfl_xor(a2, 16, 64); a2 += __shfl_xor(a2, 32, 64);
    a3 += __shfl_xor(a3, 16, 64); a3 += __shfl_xor(a3, 32, 64);
    a4 += __shfl_xor(a4, 16, 64); a4 += __shfl_xor(a4, 32, 64);
    a5 += __shfl_xor(a5, 16, 64); a5 += __shfl_xor(a5, 32, 64);
    a6 += __shfl_xor(a6, 16, 64); a6 += __shfl_xor(a6, 32, 64);
    a7 += __shfl_xor(a7, 16, 64); a7 += __shfl_xor(a7, 32, 64);
    if (quad == 0) {
        *(float4*)(out + (size_t)r * DIM + d8)     = make_float4(a0, a1, a2, a3);
        *(float4*)(out + (size_t)r * DIM + d8 + 4) = make_float4(a4, a5, a6, a7);
    }
}

// fp32 row accumulate (fallback tiers, compact-entry decode)
__global__ void row_bucket_kernel(const int* __restrict__ cnt,
                                  const unsigned* __restrict__ pk_sub,
                                  const unsigned* __restrict__ pk_sup,
                                  const float* __restrict__ diff,
                                  const float* __restrict__ inputs, const float* __restrict__ old_act,
                                  const int* __restrict__ fields,
                                  float* __restrict__ out, int nrows, int use_diff) {
    int wv = threadIdx.x >> 6, lane = threadIdx.x & 63;
    int grp = blockIdx.x & (NXCD - 1);
    int q   = blockIdx.x >> 3;
    int r   = grp + NXCD * (q * 4 + wv);
    if (r >= nrows) return;
    const int half = lane >> 5;
    const int l32  = lane & 31;
    const int d4   = l32 * 4;
    float a0 = 0.f, a1 = 0.f, a2 = 0.f, a3 = 0.f;
    {
        int e = cnt[r]; if (e > SUB_CAP) e = SUB_CAP;
        const unsigned* bp = pk_sub + (size_t)r * SUB_CAP;
        int j = 0;
        for (; j + 2 <= e; j += 2) {
            unsigned u = bp[j + half];
            int c = (int)(u >> 14);
            float v = (float)(u & 16383u) * (1.f / 16384.f);
            if (use_diff) {
                float4 g = *(const float4*)(diff + (size_t)c * DIM + d4);
                a0 += v * g.x; a1 += v * g.y; a2 += v * g.z; a3 += v * g.w;
            } else {
                int f = fields[c];
                float4 x = *(const float4*)(inputs  + (size_t)c * DIM + d4);
                float4 y = *(const float4*)(old_act + (size_t)f * DIM + d4);
                a0 += v * (x.x - y.x); a1 += v * (x.y - y.y);
                a2 += v * (x.z - y.z); a3 += v * (x.w - y.w);
            }
        }
        if (j < e && half == 0) {
            unsigned u = bp[j];
            int c = (int)(u >> 14);
            float v = (float)(u & 16383u) * (1.f / 16384.f);
            if (use_diff) {
                float4 g = *(const float4*)(diff + (size_t)c * DIM + d4);
                a0 += v * g.x; a1 += v * g.y; a2 += v * g.z; a3 += v * g.w;
            } else {
                int f = fields[c];
                float4 x = *(const float4*)(inputs  + (size_t)c * DIM + d4);
                float4 y = *(const float4*)(old_act + (size_t)f * DIM + d4);
                a0 += v * (x.x - y.x); a1 += v * (x.y - y.y);
                a2 += v * (x.z - y.z); a3 += v * (x.w - y.w);
            }
        }
    }
    {
        int e = cnt[nrows + r]; if (e > SUP_CAP) e = SUP_CAP;
        const unsigned* bp = pk_sup + (size_t)r * SUP_CAP;
        int j = 0;
        for (; j + 2 <= e; j += 2) {
            unsigned u = bp[j + half];
            int c = (int)(u >> 14);
            float v = (float)(u & 16383u) * (1.f / 16384.f);
            float4 g = *(const float4*)(old_act + (size_t)c * DIM + d4);
            a0 += v * g.x; a1 += v * g.y; a2 += v * g.z; a3 += v * g.w;
        }
        if (j < e && half == 0) {
            unsigned u = bp[j];
            int c = (int)(u >> 14);
            float v = (float)(u & 16383u) * (1.f / 16384.f);
            float4 g = *(const float4*)(old_act + (size_t)c * DIM + d4);
            a0 += v * g.x; a1 += v * g.y; a2 += v * g.z; a3 += v * g.w;
        }
    }
    float b0 = __shfl(a0, lane ^ 32, 64);
    float b1 = __shfl(a1, lane ^ 32, 64);
    float b2 = __shfl(a2, lane ^ 32, 64);
    float b3 = __shfl(a3, lane ^ 32, 64);
    if (half == 0) {
        *(float4*)(out + (size_t)r * DIM + d4) = make_float4(a0 + b0, a1 + b1, a2 + b2, a3 + b3);
    }
}

// tail: sim finalize + overflow/residual edges (mode selects gather source)
__global__ void tail_kernel(const float* __restrict__ partials, int np,
                            const int* __restrict__ cnt, const int4* __restrict__ over,
                            const float* __restrict__ diff,
                            const float* __restrict__ inputs, const float* __restrict__ old_act,
                            const int* __restrict__ fields,
                            const unsigned short* __restrict__ oa16,
                            const unsigned short* __restrict__ diff16,
                            float* __restrict__ out, int nrows, int n, int mode) {
    if (blockIdx.x == 0 && threadIdx.x < 64) {
        double dot = 0.0, nx = 0.0, ny = 0.0;
        for (int i = threadIdx.x; i < np; i += 64) {
            dot += (double)partials[i * 3 + 0];
            nx  += (double)partials[i * 3 + 1];
            ny  += (double)partials[i * 3 + 2];
        }
        for (int off = 32; off > 0; off >>= 1) {
            dot += __shfl_down(dot, off, 64);
            nx  += __shfl_down(nx,  off, 64);
            ny  += __shfl_down(ny,  off, 64);
        }
        if (threadIdx.x == 0)
            out[n] = (float)(dot / (sqrt(nx) * sqrt(ny)));
    }
    int no = cnt[2 * nrows]; if (no > OVER_MAX) no = OVER_MAX;
    int tid = blockIdx.x * blockDim.x + threadIdx.x;
    int stride = gridDim.x * blockDim.x;
    for (int i = tid; i < no; i += stride) {
        int4 t = over[i];
        int r = t.x, c = t.y, sup = t.w;
        float v = __int_as_float(t.z);
        for (int d = 0; d < DIM; ++d) {
            float term;
            if (mode == 2) {
                term = sup ? bflo((unsigned)oa16[(size_t)c * DIM + d])
                           : bflo((unsigned)diff16[(size_t)c * DIM + d]);
            } else if (sup) term = old_act[(size_t)c * DIM + d];
            else if (mode == 1) term = diff[(size_t)c * DIM + d];
            else term = inputs[(size_t)c * DIM + d] - old_act[(size_t)fields[c] * DIM + d];
            atomicAdd(&out[(size_t)r * DIM + d], v * term);
        }
    }
}

// ================= fallback: round-4 scan pipeline (proven) =================
__global__ void prep4_kernel(const float* __restrict__ inputs, const float* __restrict__ old_act,
                             const int* __restrict__ fields,
                             const int* __restrict__ sub_rows, int e_sub,
                             const int* __restrict__ sup_rows, int e_sup,
                             int* __restrict__ cnt, float* __restrict__ partials,
                             int nrows, int n2) {
    int tid = blockIdx.x * blockDim.x + threadIdx.x;
    int stride = gridDim.x * blockDim.x;
    float dot = 0.f, nx = 0.f, ny = 0.f;
    for (int i = tid; i < n2; i += stride) {
        int idx = i * 2;
        int b = idx >> 7, d = idx & (DIM - 1);
        float2 x = *(const float2*)(inputs + idx);
        int f = fields[b];
        float2 y = *(const float2*)(old_act + (size_t)f * DIM + d);
        dot += x.x * y.x + x.y * y.y;
        nx  += x.x * x.x + x.y * x.y;
        ny  += y.x * y.x + y.y * y.y;
    }
    int e_tot = e_sub + e_sup;
    for (int i = tid; i < e_tot; i += stride) {
        int r = (i < e_sub) ? sub_rows[i] : (nrows + sup_rows[i - e_sub]);
        atomicAdd(&cnt[r], 1);
    }
    for (int off = 32; off > 0; off >>= 1) {
        dot += __shfl_down(dot, off, 64);
        nx  += __shfl_down(nx,  off, 64);
        ny  += __shfl_down(ny,  off, 64);
    }
    __shared__ float s[3][4];
    int lane = threadIdx.x & 63, wv = threadIdx.x >> 6;
    if (lane == 0) { s[0][wv] = dot; s[1][wv] = nx; s[2][wv] = ny; }
    __syncthreads();
    if (threadIdx.x == 0) {
        float D = 0.f, NX = 0.f, NY = 0.f;
        for (int w = 0; w < 4; ++w) { D += s[0][w]; NX += s[1][w]; NY += s[2][w]; }
        partials[blockIdx.x * 3 + 0] = D;
        partials[blockIdx.x * 3 + 1] = NX;
        partials[blockIdx.x * 3 + 2] = NY;
    }
}

__global__ void finalize4_kernel(const float* __restrict__ partials, int np,
                                 float* __restrict__ out_sim) {
    double dot = 0.0, nx = 0.0, ny = 0.0;
    for (int i = threadIdx.x; i < np; i += 64) {
        dot += (double)partials[i * 3 + 0];
        nx  += (double)partials[i * 3 + 1];
        ny  += (double)partials[i * 3 + 2];
    }
    for (int off = 32; off > 0; off >>= 1) {
        dot += __shfl_down(dot, off, 64);
        nx  += __shfl_down(nx,  off, 64);
        ny  += __shfl_down(ny,  off, 64);
    }
    if (threadIdx.x == 0)
        *out_sim = (float)(dot / (sqrt(nx) * sqrt(ny)));
}

__global__ void scanA_kernel(const int* __restrict__ cnt, int* __restrict__ tmp,
                             int* __restrict__ bsum, int m) {
    __shared__ int s[256];
    int i = blockIdx.x * 256 + threadIdx.x;
    int v = (i < m) ? cnt[i] : 0;
    s[threadIdx.x] = v;
    __syncthreads();
    for (int d = 1; d < 256; d <<= 1) {
        int t = (threadIdx.x >= (unsigned)d) ? s[threadIdx.x - d] : 0;
        __syncthreads();
        s[threadIdx.x] += t;
        __syncthreads();
    }
    if (i < m) tmp[i] = s[threadIdx.x] - v;
    if (threadIdx.x == 255) bsum[blockIdx.x] = s[255];
}

__global__ void scanB_kernel(int* __restrict__ bsum, int* __restrict__ boff, int nb) {
    __shared__ int s[512];
    int v = (threadIdx.x < nb) ? bsum[threadIdx.x] : 0;
    s[threadIdx.x] = v;
    __syncthreads();
    for (int d = 1; d < 512; d <<= 1) {
        int t = (threadIdx.x >= (unsigned)d) ? s[threadIdx.x - d] : 0;
        __syncthreads();
        s[threadIdx.x] += t;
        __syncthreads();
    }
    if (threadIdx.x < nb) boff[threadIdx.x] = s[threadIdx.x] - v;
}

__global__ void scanC_kernel(const int* tmp, const int* __restrict__ boff,
                             int* __restrict__ off, int* cur, int m, int e_tot) {
    int i = blockIdx.x * 256 + threadIdx.x;
    if (i < m) {
        int o = tmp[i] + boff[i >> 8];
        off[i] = o;
        cur[i] = o;
    }
    if (i == 0) off[m] = e_tot;
}

__global__ void scatter4_kernel(const int* __restrict__ sub_rows, const int* __restrict__ sub_cols,
                                const float* __restrict__ sub_vals, int e_sub,
                                const int* __restrict__ sup_rows, const int* __restrict__ sup_cols,
                                const float* __restrict__ sup_vals, int e_sup,
                                int* __restrict__ cur, int2* __restrict__ pk, int nrows) {
    int i = blockIdx.x * blockDim.x + threadIdx.x;
    int e_tot = e_sub + e_sup;
    if (i >= e_tot) return;
    int r, c; float v;
    if (i < e_sub) { r = sub_rows[i]; c = sub_cols[i]; v = sub_vals[i]; }
    else { int k = i - e_sub; r = nrows + sup_rows[k]; c = sup_cols[k]; v = sup_vals[k]; }
    int pos = atomicAdd(&cur[r], 1);
    pk[pos] = make_int2(c, __float_as_int(v));
}

__global__ void row4_kernel(const int* __restrict__ off, const int2* __restrict__ pk,
                            const float* __restrict__ inputs, const float* __restrict__ old_act,
                            const int* __restrict__ fields, float* __restrict__ out, int nrows) {
    int wv = threadIdx.x >> 6, lane = threadIdx.x & 63;
    int r = blockIdx.x * (blockDim.x >> 6) + wv;
    if (r >= nrows) return;
    int d0 = lane * 2;
    float a0 = 0.f, a1 = 0.f;
    int b = off[r], e = off[r + 1];
    for (int j = b; j < e; ++j) {
        int2 p = pk[j];
        int c = p.x; float v = __int_as_float(p.y);
        int f = fields[c];
        float2 x = *(const float2*)(inputs  + (size_t)c * DIM + d0);
        float2 y = *(const float2*)(old_act + (size_t)f * DIM + d0);
        a0 += v * (x.x - y.x);
        a1 += v * (x.y - y.y);
    }
    b = off[nrows + r]; e = off[nrows + r + 1];
    for (int j = b; j < e; ++j) {
        int2 p = pk[j];
        int c = p.x; float v = __int_as_float(p.y);
        float2 y = *(const float2*)(old_act + (size_t)c * DIM + d0);
        a0 += v * y.x;
        a1 += v * y.y;
    }
    *(float2*)(out + (size_t)r * DIM + d0) = make_float2(a0, a1);
}

extern "C" void kernel_launch(void* const* d_in, const int* in_sizes, int n_in,
                              void* d_out, int out_size, void* d_ws, size_t ws_size,
                              hipStream_t stream) {
    const float* inputs   = (const float*)d_in[0];
    const float* old_act  = (const float*)d_in[1];
    const int*   fields   = (const int*)d_in[2];
    const int*   sub_rows = (const int*)d_in[3];
    const int*   sub_cols = (const int*)d_in[4];
    const float* sub_vals = (const float*)d_in[5];
    const int*   sup_rows = (const int*)d_in[6];
    const int*   sup_cols = (const int*)d_in[7];
    const float* sup_vals = (const float*)d_in[8];

    const int n     = in_sizes[0];     // BATCH * DIM
    const int nrows = n / DIM;         // BATCH
    const int n_old = in_sizes[1];     // N_DATA * DIM
    const int e_sub = in_sizes[3];
    const int e_sup = in_sizes[6];
    const int e_tot = e_sub + e_sup;

    float* out = (float*)d_out;
    char*  ws  = (char*)d_ws;

    // ---- workspace layout (compact 4B bucket entries) ----
    size_t off_part = 0;                                                // f32[PREP_GRID*3]
    size_t off_cnt  = (PREP_GRID * 3 * 4 + 63) & ~(size_t)63;           // int[2*nrows+1]
    size_t off_over = (off_cnt + (size_t)(2 * nrows + 1) * 4 + 15) & ~(size_t)15;  // int4[OVER_MAX]
    size_t off_psub = off_over + (size_t)OVER_MAX * 16;                 // u32[nrows*SUB_CAP]
    size_t off_psup = off_psub + (size_t)nrows * SUB_CAP * 4;           // u32[nrows*SUP_CAP]
    size_t off_aux  = off_psup + (size_t)nrows * SUP_CAP * 4;           // (oa16+diff16) or f32 diff
    size_t need_base = off_aux;
    size_t need_diff = off_aux + (size_t)n * 4;
    size_t off_oa16 = off_aux;                                          // u16[n_old]
    size_t off_d16  = (off_oa16 + (size_t)n_old * 2 + 15) & ~(size_t)15; // u16[n]
    size_t need16   = off_d16 + (size_t)n * 2;

    int nblk = NXCD * ((((nrows + NXCD - 1) / NXCD) + 3) / 4);

    if (ws_size >= need_base) {
        float*    partials = (float*)(ws + off_part);
        int*      cnt      = (int*)(ws + off_cnt);
        int4*     over     = (int4*)(ws + off_over);
        unsigned* pk_sub   = (unsigned*)(ws + off_psub);
        unsigned* pk_sup   = (unsigned*)(ws + off_psup);
        float*    diff     = (float*)(ws + off_aux);
        unsigned short* oa16   = (unsigned short*)(ws + off_oa16);
        unsigned short* diff16 = (unsigned short*)(ws + off_d16);
        int mode;
        if (ws_size >= need16)         mode = 2;   // bf16 gathers
        else if (ws_size >= need_diff) mode = 1;   // f32 diff
        else                           mode = 0;   // no diff buffer

        hipMemsetAsync(cnt, 0, (size_t)(2 * nrows + 1) * 4, stream);

        prep_stream_kernel<<<PREP_GRID, TPB, 0, stream>>>(
            inputs, old_act, fields, partials, diff,
            oa16, diff16, n_old / 4, mode, n / 4);

        bin_kernel<<<PREP_GRID, TPB, 0, stream>>>(
            sub_rows, sub_cols, sub_vals, e_sub,
            sup_rows, sup_cols, sup_vals, e_sup,
            cnt, pk_sub, pk_sup, over, nrows);

        if (mode == 2) {
            row_bucket16_kernel<<<nblk, TPB, 0, stream>>>(
                cnt, pk_sub, pk_sup, diff16, oa16, out, nrows);
        } else {
            row_bucket_kernel<<<nblk, TPB, 0, stream>>>(
                cnt, pk_sub, pk_sup, diff, inputs, old_act, fields, out, nrows, mode);
        }

        tail_kernel<<<32, TPB, 0, stream>>>(
            partials, PREP_GRID, cnt, over, diff, inputs, old_act, fields,
            oa16, diff16, out, nrows, n, mode);
        return;
    }

    // ---- fallback: round-4 scan pipeline ----
    const int m     = 2 * nrows;
    const int nblkA = (m + 255) / 256;
    size_t f_part = 0;
    size_t f_cnt  = (2048 * 3 * 4 + 63) & ~(size_t)63;
    size_t f_tmp  = f_cnt + (size_t)m * 4;
    size_t f_offs = f_tmp + (size_t)m * 4;
    size_t f_bsum = f_offs + (size_t)(m + 1) * 4;
    size_t f_boff = f_bsum + 4096;
    size_t f_pk   = (f_boff + 4096 + 7) & ~(size_t)7;
    size_t f_need = f_pk + (size_t)e_tot * 8;

    float* partials = (float*)(ws + f_part);
    int*   cnt      = (int*)(ws + f_cnt);
    int*   tmp      = (int*)(ws + f_tmp);
    int*   offs     = (int*)(ws + f_offs);
    int*   bsum     = (int*)(ws + f_bsum);
    int*   boff     = (int*)(ws + f_boff);
    int2*  pk       = (int2*)(ws + f_pk);

    if (ws_size >= f_need && nblkA <= 512) {
        hipMemsetAsync(cnt, 0, (size_t)m * 4, stream);
        prep4_kernel<<<2048, 256, 0, stream>>>(inputs, old_act, fields,
                                               sub_rows, e_sub, sup_rows, e_sup,
                                               cnt, partials, nrows, n / 2);
        scanA_kernel<<<nblkA, 256, 0, stream>>>(cnt, tmp, bsum, m);
        scanB_kernel<<<1, 512, 0, stream>>>(bsum, boff, nblkA);
        scanC_kernel<<<nblkA, 256, 0, stream>>>(tmp, boff, offs, tmp, m, e_tot);
        scatter4_kernel<<<(e_tot + 255) / 256, 256, 0, stream>>>(
            sub_rows, sub_cols, sub_vals, e_sub,
            sup_rows, sup_cols, sup_vals, e_sup, tmp, pk, nrows);
        row4_kernel<<<(nrows + 3) / 4, 256, 0, stream>>>(offs, pk, inputs, old_act,
                                                         fields, out, nrows);
        finalize4_kernel<<<1, 64, 0, stream>>>(partials, 2048, out + n);
    }
}

// Round 10
// 368.284 us; speedup vs baseline: 1.0003x; 1.0003x over previous
//
#include <hip/hip_runtime.h>
#include <math.h>

#define DIM 128
#define TPB 256
#define PREP_GRID 2048
#define SUB_CAP 32
#define SUP_CAP 64
#define OVER_MAX 65536
#define NXCD 8

// ---- non-temporal (evict-first) access helpers ----
// __builtin_nontemporal_* requires scalar or NATIVE clang vector types;
// HIP_vector_type structs are rejected (R9 compile error). Use ext_vector_type
// shims and convert in registers.
typedef float          nv_f4  __attribute__((ext_vector_type(4)));
typedef int            nv_i4  __attribute__((ext_vector_type(4)));
typedef unsigned short nv_us4 __attribute__((ext_vector_type(4)));

__device__ __forceinline__ float4 ntload4f(const float* p) {
    nv_f4 v = __builtin_nontemporal_load((const nv_f4*)p);
    return make_float4(v.x, v.y, v.z, v.w);
}
__device__ __forceinline__ int4 ntload4i(const int* p) {
    nv_i4 v = __builtin_nontemporal_load((const nv_i4*)p);
    return make_int4(v.x, v.y, v.z, v.w);
}
__device__ __forceinline__ int   ntloadi(const int* p)   { return __builtin_nontemporal_load(p); }
__device__ __forceinline__ float ntloadf(const float* p) { return __builtin_nontemporal_load(p); }
__device__ __forceinline__ unsigned ntloadu(const unsigned* p) { return __builtin_nontemporal_load(p); }
__device__ __forceinline__ void ntstore4us(unsigned short* p, ushort4 v) {
    nv_us4 t = {v.x, v.y, v.z, v.w};
    __builtin_nontemporal_store(t, (nv_us4*)p);
}
__device__ __forceinline__ void ntstore4f(float* p, float4 v) {
    nv_f4 t = {v.x, v.y, v.z, v.w};
    __builtin_nontemporal_store(t, (nv_f4*)p);
}

// bf16 helpers: round-to-nearest-even pack, cheap unpack (hi half is a free AND)
__device__ __forceinline__ unsigned short f2bf(float f) {
    unsigned u = __float_as_uint(f);
    u += 0x7fffu + ((u >> 16) & 1u);
    return (unsigned short)(u >> 16);
}
__device__ __forceinline__ float bflo(unsigned u) { return __uint_as_float(u << 16); }
__device__ __forceinline__ float bfhi(unsigned u) { return __uint_as_float(u & 0xffff0000u); }

// compact bucket entry: (c << 14) | q, q = round(v * 16384), v in [0,1).
// Out-of-range v: quantized-clamped entry + EXACT fp32 residual edge via the
// overflow list -> correct for arbitrary inputs.
__device__ __forceinline__ void put_edge(int r, int c, float v, int pos, int sup,
                                         unsigned* __restrict__ pk, int cap,
                                         int* __restrict__ over_cnt, int4* __restrict__ over) {
    if (pos < cap) {
        float vc = fminf(fmaxf(v, 0.f), 16383.5f / 16384.f);
        int q = (int)fmaf(vc, 16384.f, 0.5f);
        if (q > 16383) q = 16383;
        pk[(size_t)r * cap + pos] = ((unsigned)c << 14) | (unsigned)q;   // cached store
        float resid = v - (float)q * (1.f / 16384.f);   // exact: q/2^14 exact in fp32
        if (fabsf(resid) > 1.2e-4f) {                    // only out-of-range v trips this
            int op = atomicAdd(over_cnt, 1);
            if (op < OVER_MAX) over[op] = make_int4(r, c, __float_as_int(resid), sup);
        }
    } else {
        int op = atomicAdd(over_cnt, 1);
        if (op < OVER_MAX) over[op] = make_int4(r, c, __float_as_int(v), sup);
    }
}

// ================= primary path =================
// prep (fused, R6 structure = best measured): sim partials + diff precompute
// + oa16 conversion + XCD-partitioned bucket binning. All streaming accesses
// use nt hints so bucket lines (~1.9MB/XCD) stay L2-resident until full
// (R6/R7 evidence: pollution, not atomics, is the binning cost).
__global__ void prep_bin_kernel(const float* __restrict__ inputs,
                                const float* __restrict__ old_act,
                                const int* __restrict__ fields,
                                const int* __restrict__ sub_rows, const int* __restrict__ sub_cols,
                                const float* __restrict__ sub_vals, int e_sub,
                                const int* __restrict__ sup_rows, const int* __restrict__ sup_cols,
                                const float* __restrict__ sup_vals, int e_sup,
                                int* __restrict__ cnt,            // [2*nrows] + over_cnt at [2*nrows]
                                unsigned* __restrict__ pk_sub, unsigned* __restrict__ pk_sup,
                                int4* __restrict__ over,
                                float* __restrict__ partials, float* __restrict__ diff,
                                unsigned short* __restrict__ oa16,
                                unsigned short* __restrict__ diff16, int n_old4,
                                int mode, int nrows, int n4) {
    int tid = blockIdx.x * blockDim.x + threadIdx.x;
    int stride = gridDim.x * blockDim.x;
    int* over_cnt = cnt + 2 * nrows;

    // sim + diff (float4 in, diff out as f32 or bf16) — all streaming: nt
    float dot = 0.f, nx = 0.f, ny = 0.f;
    for (int i = tid; i < n4; i += stride) {
        int idx = i * 4;
        int b = idx >> 7, d = idx & (DIM - 1);
        float4 x = ntload4f(inputs + idx);
        int f = fields[b];                                  // reused 32x/row: cached
        float4 y = ntload4f(old_act + (size_t)f * DIM + d);
        dot += x.x * y.x + x.y * y.y + x.z * y.z + x.w * y.w;
        nx  += x.x * x.x + x.y * x.y + x.z * x.z + x.w * x.w;
        ny  += y.x * y.x + y.y * y.y + y.z * y.z + y.w * y.w;
        if (mode == 2) {
            ntstore4us(diff16 + idx,
                       make_ushort4(f2bf(x.x - y.x), f2bf(x.y - y.y),
                                    f2bf(x.z - y.z), f2bf(x.w - y.w)));
        } else if (mode == 1) {
            ntstore4f(diff + idx,
                      make_float4(x.x - y.x, x.y - y.y, x.z - y.z, x.w - y.w));
        }
    }

    // old_act -> bf16 copy (mode 2): pure streaming: nt both sides
    if (mode == 2) {
        for (int i = tid; i < n_old4; i += stride) {
            int idx = i * 4;
            float4 y = ntload4f(old_act + idx);
            ntstore4us(oa16 + idx,
                       make_ushort4(f2bf(y.x), f2bf(y.y), f2bf(y.z), f2bf(y.w)));
        }
    }

    // XCD-partitioned binning: group x = blocks with blockIdx&7==x bins rows
    // r&7==x. Edge-array scan is 8x-redundant streaming: nt loads so it does
    // NOT evict the group's partially-filled bucket lines.
    int grp     = blockIdx.x & (NXCD - 1);
    int gblk    = blockIdx.x >> 3;
    int gtid    = gblk * blockDim.x + threadIdx.x;
    int gstride = (gridDim.x >> 3) * blockDim.x;

#define BIN_SCAN(ROWS, COLS, VALS, E, SUP, CBASE, PK, CAP)                              \
    {                                                                                   \
        int e4 = (E) & ~3;                                                              \
        for (int i = gtid * 4; i < e4; i += gstride * 4) {                              \
            int4 rr = ntload4i((ROWS) + i);                                             \
            bool m0 = (rr.x & (NXCD - 1)) == grp;                                       \
            bool m1 = (rr.y & (NXCD - 1)) == grp;                                       \
            bool m2 = (rr.z & (NXCD - 1)) == grp;                                       \
            bool m3 = (rr.w & (NXCD - 1)) == grp;                                       \
            int p0 = 0, p1 = 0, p2 = 0, p3 = 0;                                         \
            int c0 = 0, c1 = 0, c2 = 0, c3 = 0;                                         \
            float v0 = 0.f, v1 = 0.f, v2 = 0.f, v3 = 0.f;                               \
            /* issue phase: loads + atomics, no use of returned positions */            \
            if (m0) { c0 = ntloadi((COLS) + i);     v0 = ntloadf((VALS) + i);     p0 = atomicAdd(&cnt[(CBASE) + rr.x], 1); } \
            if (m1) { c1 = ntloadi((COLS) + i + 1); v1 = ntloadf((VALS) + i + 1); p1 = atomicAdd(&cnt[(CBASE) + rr.y], 1); } \
            if (m2) { c2 = ntloadi((COLS) + i + 2); v2 = ntloadf((VALS) + i + 2); p2 = atomicAdd(&cnt[(CBASE) + rr.z], 1); } \
            if (m3) { c3 = ntloadi((COLS) + i + 3); v3 = ntloadf((VALS) + i + 3); p3 = atomicAdd(&cnt[(CBASE) + rr.w], 1); } \
            /* drain phase: dependent stores (cached, want them in L2) */               \
            if (m0) put_edge(rr.x, c0, v0, p0, (SUP), (PK), (CAP), over_cnt, over);     \
            if (m1) put_edge(rr.y, c1, v1, p1, (SUP), (PK), (CAP), over_cnt, over);     \
            if (m2) put_edge(rr.z, c2, v2, p2, (SUP), (PK), (CAP), over_cnt, over);     \
            if (m3) put_edge(rr.w, c3, v3, p3, (SUP), (PK), (CAP), over_cnt, over);     \
        }                                                                               \
        for (int i = e4 + gtid; i < (E); i += gstride) {                                \
            int r = (ROWS)[i];                                                          \
            if ((r & (NXCD - 1)) == grp) {                                              \
                int c = (COLS)[i]; float v = (VALS)[i];                                 \
                int p = atomicAdd(&cnt[(CBASE) + r], 1);                                \
                put_edge(r, c, v, p, (SUP), (PK), (CAP), over_cnt, over);               \
            }                                                                           \
        }                                                                               \
    }

    BIN_SCAN(sub_rows, sub_cols, sub_vals, e_sub, 0, 0,     pk_sub, SUB_CAP)
    BIN_SCAN(sup_rows, sup_cols, sup_vals, e_sup, 1, nrows, pk_sup, SUP_CAP)
#undef BIN_SCAN

    // block-reduce sim
    for (int off = 32; off > 0; off >>= 1) {
        dot += __shfl_down(dot, off, 64);
        nx  += __shfl_down(nx,  off, 64);
        ny  += __shfl_down(ny,  off, 64);
    }
    __shared__ float s[3][4];
    int lane = threadIdx.x & 63, wv = threadIdx.x >> 6;
    if (lane == 0) { s[0][wv] = dot; s[1][wv] = nx; s[2][wv] = ny; }
    __syncthreads();
    if (threadIdx.x == 0) {
        float D = 0.f, NX = 0.f, NY = 0.f;
        for (int w = 0; w < 4; ++w) { D += s[0][w]; NX += s[1][w]; NY += s[2][w]; }
        partials[blockIdx.x * 3 + 0] = D;
        partials[blockIdx.x * 3 + 1] = NX;
        partials[blockIdx.x * 3 + 2] = NY;
    }
}

// bf16 row accumulate: one wave per row, XCD-affine mapping.
// 16-lane quad gathers: quad q (lanes 16q..16q+15) handles edge j+q; each lane
// loads uint4 = 8 bf16 dims -> a row is 16 requests of 16B, 4 edges per
// wave-step. Bucket reads are read-once: nt. Gathers carry reuse: cached.
__global__ void row_bucket16_kernel(const int* __restrict__ cnt,
                                    const unsigned* __restrict__ pk_sub,
                                    const unsigned* __restrict__ pk_sup,
                                    const unsigned short* __restrict__ diff16,
                                    const unsigned short* __restrict__ oa16,
                                    float* __restrict__ out, int nrows) {
    int wv = threadIdx.x >> 6, lane = threadIdx.x & 63;
    int grp = blockIdx.x & (NXCD - 1);
    int qb  = blockIdx.x >> 3;
    int r   = grp + NXCD * (qb * 4 + wv);
    if (r >= nrows) return;
    const int quad = lane >> 4;        // 0..3 : edge slot
    const int l16  = lane & 15;
    const int d8   = l16 * 8;          // dims [d8 .. d8+7]
    float a0 = 0.f, a1 = 0.f, a2 = 0.f, a3 = 0.f;
    float a4 = 0.f, a5 = 0.f, a6 = 0.f, a7 = 0.f;

#define GATH8(SRC, U)                                                       \
    {                                                                       \
        int   c_ = (int)((U) >> 14);                                        \
        float v_ = (float)((U) & 16383u) * (1.f / 16384.f);                 \
        uint4 g_ = *(const uint4*)((SRC) + ((size_t)c_ << 7) + d8);         \
        a0 += v_ * bflo(g_.x); a1 += v_ * bfhi(g_.x);                       \
        a2 += v_ * bflo(g_.y); a3 += v_ * bfhi(g_.y);                       \
        a4 += v_ * bflo(g_.z); a5 += v_ * bfhi(g_.z);                       \
        a6 += v_ * bflo(g_.w); a7 += v_ * bfhi(g_.w);                       \
    }

    // ---- sub edges (diff16) ----
    {
        int e = cnt[r]; if (e > SUB_CAP) e = SUB_CAP;
        const unsigned* bp = pk_sub + (size_t)r * SUB_CAP;
        int j = 0;
        for (; j + 8 <= e; j += 8) {
            unsigned u0 = ntloadu(bp + j + quad);
            unsigned u1 = ntloadu(bp + j + 4 + quad);
            GATH8(diff16, u0); GATH8(diff16, u1);
        }
        for (; j + 4 <= e; j += 4) {
            unsigned u0 = ntloadu(bp + j + quad);
            GATH8(diff16, u0);
        }
        int rem = e - j;
        if (quad < rem) {
            unsigned u0 = ntloadu(bp + j + quad);
            GATH8(diff16, u0);
        }
    }
    // ---- sup edges (oa16) ----
    {
        int e = cnt[nrows + r]; if (e > SUP_CAP) e = SUP_CAP;
        const unsigned* bp = pk_sup + (size_t)r * SUP_CAP;
        int j = 0;
        for (; j + 16 <= e; j += 16) {
            unsigned u0 = ntloadu(bp + j + quad);
            unsigned u1 = ntloadu(bp + j + 4 + quad);
            unsigned u2 = ntloadu(bp + j + 8 + quad);
            unsigned u3 = ntloadu(bp + j + 12 + quad);
            GATH8(oa16, u0); GATH8(oa16, u1); GATH8(oa16, u2); GATH8(oa16, u3);
        }
        for (; j + 4 <= e; j += 4) {
            unsigned u0 = ntloadu(bp + j + quad);
            GATH8(oa16, u0);
        }
        int rem = e - j;
        if (quad < rem) {
            unsigned u0 = ntloadu(bp + j + quad);
            GATH8(oa16, u0);
        }
    }
#undef GATH8
    // fold the 4 quads
    a0 += __shfl_xor(a0, 16, 64); a0 += __shfl_xor(a0, 32, 64);
    a1 += __shfl_xor(a1, 16, 64); a1 += __shfl_xor(a1, 32, 64);
    a2 += __shfl_xor(a2, 16, 64); a2 += __shfl_xor(a2, 32, 64);
    a3 += __shfl_xor(a3, 16, 64); a3 += __shfl_xor(a3, 32, 64);
    a4 += __shfl_xor(a4, 16, 64); a4 += __shfl_xor(a4, 32, 64);
    a5 += __shfl_xor(a5, 16, 64); a5 += __shfl_xor(a5, 32, 64);
    a6 += __shfl_xor(a6, 16, 64); a6 += __shfl_xor(a6, 32, 64);
    a7 += __shfl_xor(a7, 16, 64); a7 += __shfl_xor(a7, 32, 64);
    if (quad == 0) {
        *(float4*)(out + (size_t)r * DIM + d8)     = make_float4(a0, a1, a2, a3);
        *(float4*)(out + (size_t)r * DIM + d8 + 4) = make_float4(a4, a5, a6, a7);
    }
}

// fp32 row accumulate (fallback tiers, compact-entry decode)
__global__ void row_bucket_kernel(const int* __restrict__ cnt,
                                  const unsigned* __restrict__ pk_sub,
                                  const unsigned* __restrict__ pk_sup,
                                  const float* __restrict__ diff,
                                  const float* __restrict__ inputs, const float* __restrict__ old_act,
                                  const int* __restrict__ fields,
                                  float* __restrict__ out, int nrows, int use_diff) {
    int wv = threadIdx.x >> 6, lane = threadIdx.x & 63;
    int grp = blockIdx.x & (NXCD - 1);
    int q   = blockIdx.x >> 3;
    int r   = grp + NXCD * (q * 4 + wv);
    if (r >= nrows) return;
    const int half = lane >> 5;
    const int l32  = lane & 31;
    const int d4   = l32 * 4;
    float a0 = 0.f, a1 = 0.f, a2 = 0.f, a3 = 0.f;
    {
        int e = cnt[r]; if (e > SUB_CAP) e = SUB_CAP;
        const unsigned* bp = pk_sub + (size_t)r * SUB_CAP;
        int j = 0;
        for (; j + 2 <= e; j += 2) {
            unsigned u = bp[j + half];
            int c = (int)(u >> 14);
            float v = (float)(u & 16383u) * (1.f / 16384.f);
            if (use_diff) {
                float4 g = *(const float4*)(diff + (size_t)c * DIM + d4);
                a0 += v * g.x; a1 += v * g.y; a2 += v * g.z; a3 += v * g.w;
            } else {
                int f = fields[c];
                float4 x = *(const float4*)(inputs  + (size_t)c * DIM + d4);
                float4 y = *(const float4*)(old_act + (size_t)f * DIM + d4);
                a0 += v * (x.x - y.x); a1 += v * (x.y - y.y);
                a2 += v * (x.z - y.z); a3 += v * (x.w - y.w);
            }
        }
        if (j < e && half == 0) {
            unsigned u = bp[j];
            int c = (int)(u >> 14);
            float v = (float)(u & 16383u) * (1.f / 16384.f);
            if (use_diff) {
                float4 g = *(const float4*)(diff + (size_t)c * DIM + d4);
                a0 += v * g.x; a1 += v * g.y; a2 += v * g.z; a3 += v * g.w;
            } else {
                int f = fields[c];
                float4 x = *(const float4*)(inputs  + (size_t)c * DIM + d4);
                float4 y = *(const float4*)(old_act + (size_t)f * DIM + d4);
                a0 += v * (x.x - y.x); a1 += v * (x.y - y.y);
                a2 += v * (x.z - y.z); a3 += v * (x.w - y.w);
            }
        }
    }
    {
        int e = cnt[nrows + r]; if (e > SUP_CAP) e = SUP_CAP;
        const unsigned* bp = pk_sup + (size_t)r * SUP_CAP;
        int j = 0;
        for (; j + 2 <= e; j += 2) {
            unsigned u = bp[j + half];
            int c = (int)(u >> 14);
            float v = (float)(u & 16383u) * (1.f / 16384.f);
            float4 g = *(const float4*)(old_act + (size_t)c * DIM + d4);
            a0 += v * g.x; a1 += v * g.y; a2 += v * g.z; a3 += v * g.w;
        }
        if (j < e && half == 0) {
            unsigned u = bp[j];
            int c = (int)(u >> 14);
            float v = (float)(u & 16383u) * (1.f / 16384.f);
            float4 g = *(const float4*)(old_act + (size_t)c * DIM + d4);
            a0 += v * g.x; a1 += v * g.y; a2 += v * g.z; a3 += v * g.w;
        }
    }
    float b0 = __shfl(a0, lane ^ 32, 64);
    float b1 = __shfl(a1, lane ^ 32, 64);
    float b2 = __shfl(a2, lane ^ 32, 64);
    float b3 = __shfl(a3, lane ^ 32, 64);
    if (half == 0) {
        *(float4*)(out + (size_t)r * DIM + d4) = make_float4(a0 + b0, a1 + b1, a2 + b2, a3 + b3);
    }
}

// tail: sim finalize + overflow/residual edges (mode selects gather source)
__global__ void tail_kernel(const float* __restrict__ partials, int np,
                            const int* __restrict__ cnt, const int4* __restrict__ over,
                            const float* __restrict__ diff,
                            const float* __restrict__ inputs, const float* __restrict__ old_act,
                            const int* __restrict__ fields,
                            const unsigned short* __restrict__ oa16,
                            const unsigned short* __restrict__ diff16,
                            float* __restrict__ out, int nrows, int n, int mode) {
    if (blockIdx.x == 0 && threadIdx.x < 64) {
        double dot = 0.0, nx = 0.0, ny = 0.0;
        for (int i = threadIdx.x; i < np; i += 64) {
            dot += (double)partials[i * 3 + 0];
            nx  += (double)partials[i * 3 + 1];
            ny  += (double)partials[i * 3 + 2];
        }
        for (int off = 32; off > 0; off >>= 1) {
            dot += __shfl_down(dot, off, 64);
            nx  += __shfl_down(nx,  off, 64);
            ny  += __shfl_down(ny,  off, 64);
        }
        if (threadIdx.x == 0)
            out[n] = (float)(dot / (sqrt(nx) * sqrt(ny)));
    }
    int no = cnt[2 * nrows]; if (no > OVER_MAX) no = OVER_MAX;
    int tid = blockIdx.x * blockDim.x + threadIdx.x;
    int stride = gridDim.x * blockDim.x;
    for (int i = tid; i < no; i += stride) {
        int4 t = over[i];
        int r = t.x, c = t.y, sup = t.w;
        float v = __int_as_float(t.z);
        for (int d = 0; d < DIM; ++d) {
            float term;
            if (mode == 2) {
                term = sup ? bflo((unsigned)oa16[(size_t)c * DIM + d])
                           : bflo((unsigned)diff16[(size_t)c * DIM + d]);
            } else if (sup) term = old_act[(size_t)c * DIM + d];
            else if (mode == 1) term = diff[(size_t)c * DIM + d];
            else term = inputs[(size_t)c * DIM + d] - old_act[(size_t)fields[c] * DIM + d];
            atomicAdd(&out[(size_t)r * DIM + d], v * term);
        }
    }
}

// ================= fallback: round-4 scan pipeline (proven) =================
__global__ void prep4_kernel(const float* __restrict__ inputs, const float* __restrict__ old_act,
                             const int* __restrict__ fields,
                             const int* __restrict__ sub_rows, int e_sub,
                             const int* __restrict__ sup_rows, int e_sup,
                             int* __restrict__ cnt, float* __restrict__ partials,
                             int nrows, int n2) {
    int tid = blockIdx.x * blockDim.x + threadIdx.x;
    int stride = gridDim.x * blockDim.x;
    float dot = 0.f, nx = 0.f, ny = 0.f;
    for (int i = tid; i < n2; i += stride) {
        int idx = i * 2;
        int b = idx >> 7, d = idx & (DIM - 1);
        float2 x = *(const float2*)(inputs + idx);
        int f = fields[b];
        float2 y = *(const float2*)(old_act + (size_t)f * DIM + d);
        dot += x.x * y.x + x.y * y.y;
        nx  += x.x * x.x + x.y * x.y;
        ny  += y.x * y.x + y.y * y.y;
    }
    int e_tot = e_sub + e_sup;
    for (int i = tid; i < e_tot; i += stride) {
        int r = (i < e_sub) ? sub_rows[i] : (nrows + sup_rows[i - e_sub]);
        atomicAdd(&cnt[r], 1);
    }
    for (int off = 32; off > 0; off >>= 1) {
        dot += __shfl_down(dot, off, 64);
        nx  += __shfl_down(nx,  off, 64);
        ny  += __shfl_down(ny,  off, 64);
    }
    __shared__ float s[3][4];
    int lane = threadIdx.x & 63, wv = threadIdx.x >> 6;
    if (lane == 0) { s[0][wv] = dot; s[1][wv] = nx; s[2][wv] = ny; }
    __syncthreads();
    if (threadIdx.x == 0) {
        float D = 0.f, NX = 0.f, NY = 0.f;
        for (int w = 0; w < 4; ++w) { D += s[0][w]; NX += s[1][w]; NY += s[2][w]; }
        partials[blockIdx.x * 3 + 0] = D;
        partials[blockIdx.x * 3 + 1] = NX;
        partials[blockIdx.x * 3 + 2] = NY;
    }
}

__global__ void finalize4_kernel(const float* __restrict__ partials, int np,
                                 float* __restrict__ out_sim) {
    double dot = 0.0, nx = 0.0, ny = 0.0;
    for (int i = threadIdx.x; i < np; i += 64) {
        dot += (double)partials[i * 3 + 0];
        nx  += (double)partials[i * 3 + 1];
        ny  += (double)partials[i * 3 + 2];
    }
    for (int off = 32; off > 0; off >>= 1) {
        dot += __shfl_down(dot, off, 64);
        nx  += __shfl_down(nx,  off, 64);
        ny  += __shfl_down(ny,  off, 64);
    }
    if (threadIdx.x == 0)
        *out_sim = (float)(dot / (sqrt(nx) * sqrt(ny)));
}

__global__ void scanA_kernel(const int* __restrict__ cnt, int* __restrict__ tmp,
                             int* __restrict__ bsum, int m) {
    __shared__ int s[256];
    int i = blockIdx.x * 256 + threadIdx.x;
    int v = (i < m) ? cnt[i] : 0;
    s[threadIdx.x] = v;
    __syncthreads();
    for (int d = 1; d < 256; d <<= 1) {
        int t = (threadIdx.x >= (unsigned)d) ? s[threadIdx.x - d] : 0;
        __syncthreads();
        s[threadIdx.x] += t;
        __syncthreads();
    }
    if (i < m) tmp[i] = s[threadIdx.x] - v;
    if (threadIdx.x == 255) bsum[blockIdx.x] = s[255];
}

__global__ void scanB_kernel(int* __restrict__ bsum, int* __restrict__ boff, int nb) {
    __shared__ int s[512];
    int v = (threadIdx.x < nb) ? bsum[threadIdx.x] : 0;
    s[threadIdx.x] = v;
    __syncthreads();
    for (int d = 1; d < 512; d <<= 1) {
        int t = (threadIdx.x >= (unsigned)d) ? s[threadIdx.x - d] : 0;
        __syncthreads();
        s[threadIdx.x] += t;
        __syncthreads();
    }
    if (threadIdx.x < nb) boff[threadIdx.x] = s[threadIdx.x] - v;
}

__global__ void scanC_kernel(const int* tmp, const int* __restrict__ boff,
                             int* __restrict__ off, int* cur, int m, int e_tot) {
    int i = blockIdx.x * 256 + threadIdx.x;
    if (i < m) {
        int o = tmp[i] + boff[i >> 8];
        off[i] = o;
        cur[i] = o;
    }
    if (i == 0) off[m] = e_tot;
}

__global__ void scatter4_kernel(const int* __restrict__ sub_rows, const int* __restrict__ sub_cols,
                                const float* __restrict__ sub_vals, int e_sub,
                                const int* __restrict__ sup_rows, const int* __restrict__ sup_cols,
                                const float* __restrict__ sup_vals, int e_sup,
                                int* __restrict__ cur, int2* __restrict__ pk, int nrows) {
    int i = blockIdx.x * blockDim.x + threadIdx.x;
    int e_tot = e_sub + e_sup;
    if (i >= e_tot) return;
    int r, c; float v;
    if (i < e_sub) { r = sub_rows[i]; c = sub_cols[i]; v = sub_vals[i]; }
    else { int k = i - e_sub; r = nrows + sup_rows[k]; c = sup_cols[k]; v = sup_vals[k]; }
    int pos = atomicAdd(&cur[r], 1);
    pk[pos] = make_int2(c, __float_as_int(v));
}

__global__ void row4_kernel(const int* __restrict__ off, const int2* __restrict__ pk,
                            const float* __restrict__ inputs, const float* __restrict__ old_act,
                            const int* __restrict__ fields, float* __restrict__ out, int nrows) {
    int wv = threadIdx.x >> 6, lane = threadIdx.x & 63;
    int r = blockIdx.x * (blockDim.x >> 6) + wv;
    if (r >= nrows) return;
    int d0 = lane * 2;
    float a0 = 0.f, a1 = 0.f;
    int b = off[r], e = off[r + 1];
    for (int j = b; j < e; ++j) {
        int2 p = pk[j];
        int c = p.x; float v = __int_as_float(p.y);
        int f = fields[c];
        float2 x = *(const float2*)(inputs  + (size_t)c * DIM + d0);
        float2 y = *(const float2*)(old_act + (size_t)f * DIM + d0);
        a0 += v * (x.x - y.x);
        a1 += v * (x.y - y.y);
    }
    b = off[nrows + r]; e = off[nrows + r + 1];
    for (int j = b; j < e; ++j) {
        int2 p = pk[j];
        int c = p.x; float v = __int_as_float(p.y);
        float2 y = *(const float2*)(old_act + (size_t)c * DIM + d0);
        a0 += v * y.x;
        a1 += v * y.y;
    }
    *(float2*)(out + (size_t)r * DIM + d0) = make_float2(a0, a1);
}

extern "C" void kernel_launch(void* const* d_in, const int* in_sizes, int n_in,
                              void* d_out, int out_size, void* d_ws, size_t ws_size,
                              hipStream_t stream) {
    const float* inputs   = (const float*)d_in[0];
    const float* old_act  = (const float*)d_in[1];
    const int*   fields   = (const int*)d_in[2];
    const int*   sub_rows = (const int*)d_in[3];
    const int*   sub_cols = (const int*)d_in[4];
    const float* sub_vals = (const float*)d_in[5];
    const int*   sup_rows = (const int*)d_in[6];
    const int*   sup_cols = (const int*)d_in[7];
    const float* sup_vals = (const float*)d_in[8];

    const int n     = in_sizes[0];     // BATCH * DIM
    const int nrows = n / DIM;         // BATCH
    const int n_old = in_sizes[1];     // N_DATA * DIM
    const int e_sub = in_sizes[3];
    const int e_sup = in_sizes[6];
    const int e_tot = e_sub + e_sup;

    float* out = (float*)d_out;
    char*  ws  = (char*)d_ws;

    // ---- workspace layout (compact 4B bucket entries) ----
    size_t off_part = 0;                                                // f32[PREP_GRID*3]
    size_t off_cnt  = (PREP_GRID * 3 * 4 + 63) & ~(size_t)63;           // int[2*nrows+1]
    size_t off_over = (off_cnt + (size_t)(2 * nrows + 1) * 4 + 15) & ~(size_t)15;  // int4[OVER_MAX]
    size_t off_psub = off_over + (size_t)OVER_MAX * 16;                 // u32[nrows*SUB_CAP]
    size_t off_psup = off_psub + (size_t)nrows * SUB_CAP * 4;           // u32[nrows*SUP_CAP]
    size_t off_aux  = off_psup + (size_t)nrows * SUP_CAP * 4;           // (oa16+diff16) or f32 diff
    size_t need_base = off_aux;
    size_t need_diff = off_aux + (size_t)n * 4;
    size_t off_oa16 = off_aux;                                          // u16[n_old]
    size_t off_d16  = (off_oa16 + (size_t)n_old * 2 + 15) & ~(size_t)15; // u16[n]
    size_t need16   = off_d16 + (size_t)n * 2;

    int nblk = NXCD * ((((nrows + NXCD - 1) / NXCD) + 3) / 4);

    if (ws_size >= need_base) {
        float*    partials = (float*)(ws + off_part);
        int*      cnt      = (int*)(ws + off_cnt);
        int4*     over     = (int4*)(ws + off_over);
        unsigned* pk_sub   = (unsigned*)(ws + off_psub);
        unsigned* pk_sup   = (unsigned*)(ws + off_psup);
        float*    diff     = (float*)(ws + off_aux);
        unsigned short* oa16   = (unsigned short*)(ws + off_oa16);
        unsigned short* diff16 = (unsigned short*)(ws + off_d16);
        int mode;
        if (ws_size >= need16)         mode = 2;   // bf16 gathers
        else if (ws_size >= need_diff) mode = 1;   // f32 diff
        else                           mode = 0;   // no diff buffer

        hipMemsetAsync(cnt, 0, (size_t)(2 * nrows + 1) * 4, stream);

        prep_bin_kernel<<<PREP_GRID, TPB, 0, stream>>>(
            inputs, old_act, fields,
            sub_rows, sub_cols, sub_vals, e_sub,
            sup_rows, sup_cols, sup_vals, e_sup,
            cnt, pk_sub, pk_sup, over, partials, diff,
            oa16, diff16, n_old / 4, mode, nrows, n / 4);

        if (mode == 2) {
            row_bucket16_kernel<<<nblk, TPB, 0, stream>>>(
                cnt, pk_sub, pk_sup, diff16, oa16, out, nrows);
        } else {
            row_bucket_kernel<<<nblk, TPB, 0, stream>>>(
                cnt, pk_sub, pk_sup, diff, inputs, old_act, fields, out, nrows, mode);
        }

        tail_kernel<<<32, TPB, 0, stream>>>(
            partials, PREP_GRID, cnt, over, diff, inputs, old_act, fields,
            oa16, diff16, out, nrows, n, mode);
        return;
    }

    // ---- fallback: round-4 scan pipeline ----
    const int m     = 2 * nrows;
    const int nblkA = (m + 255) / 256;
    size_t f_part = 0;
    size_t f_cnt  = (2048 * 3 * 4 + 63) & ~(size_t)63;
    size_t f_tmp  = f_cnt + (size_t)m * 4;
    size_t f_offs = f_tmp + (size_t)m * 4;
    size_t f_bsum = f_offs + (size_t)(m + 1) * 4;
    size_t f_boff = f_bsum + 4096;
    size_t f_pk   = (f_boff + 4096 + 7) & ~(size_t)7;
    size_t f_need = f_pk + (size_t)e_tot * 8;

    float* partials = (float*)(ws + f_part);
    int*   cnt      = (int*)(ws + f_cnt);
    int*   tmp      = (int*)(ws + f_tmp);
    int*   offs     = (int*)(ws + f_offs);
    int*   bsum     = (int*)(ws + f_bsum);
    int*   boff     = (int*)(ws + f_boff);
    int2*  pk       = (int2*)(ws + f_pk);

    if (ws_size >= f_need && nblkA <= 512) {
        hipMemsetAsync(cnt, 0, (size_t)m * 4, stream);
        prep4_kernel<<<2048, 256, 0, stream>>>(inputs, old_act, fields,
                                               sub_rows, e_sub, sup_rows, e_sup,
                                               cnt, partials, nrows, n / 2);
        scanA_kernel<<<nblkA, 256, 0, stream>>>(cnt, tmp, bsum, m);
        scanB_kernel<<<1, 512, 0, stream>>>(bsum, boff, nblkA);
        scanC_kernel<<<nblkA, 256, 0, stream>>>(tmp, boff, offs, tmp, m, e_tot);
        scatter4_kernel<<<(e_tot + 255) / 256, 256, 0, stream>>>(
            sub_rows, sub_cols, sub_vals, e_sub,
            sup_rows, sup_cols, sup_vals, e_sup, tmp, pk, nrows);
        row4_kernel<<<(nrows + 3) / 4, 256, 0, stream>>>(offs, pk, inputs, old_act,
                                                         fields, out, nrows);
        finalize4_kernel<<<1, 64, 0, stream>>>(partials, 2048, out + n);
    }
}

// Round 11
// 365.898 us; speedup vs baseline: 1.0069x; 1.0065x over previous
//
#include <hip/hip_runtime.h>
#include <math.h>

#define DIM 128
#define TPB 256
#define PREP_GRID 2048
#define SUB_CAP 32
#define SUP_CAP 64
#define OVER_MAX 65536
#define NXCD 8

// ---- non-temporal (evict-first) access helpers ----
// Measured (R10): nt on prep's STREAMING phase = -8us on prep_bin.
// nt on row16's bucket reads = ~+16us regression -> reverted (this round).
// __builtin_nontemporal_* requires scalar or NATIVE clang vector types;
// HIP_vector_type structs are rejected. ext_vector_type shims convert in regs.
typedef float          nv_f4  __attribute__((ext_vector_type(4)));
typedef int            nv_i4  __attribute__((ext_vector_type(4)));
typedef unsigned short nv_us4 __attribute__((ext_vector_type(4)));

__device__ __forceinline__ float4 ntload4f(const float* p) {
    nv_f4 v = __builtin_nontemporal_load((const nv_f4*)p);
    return make_float4(v.x, v.y, v.z, v.w);
}
__device__ __forceinline__ int4 ntload4i(const int* p) {
    nv_i4 v = __builtin_nontemporal_load((const nv_i4*)p);
    return make_int4(v.x, v.y, v.z, v.w);
}
__device__ __forceinline__ int   ntloadi(const int* p)   { return __builtin_nontemporal_load(p); }
__device__ __forceinline__ float ntloadf(const float* p) { return __builtin_nontemporal_load(p); }
__device__ __forceinline__ void ntstore4us(unsigned short* p, ushort4 v) {
    nv_us4 t = {v.x, v.y, v.z, v.w};
    __builtin_nontemporal_store(t, (nv_us4*)p);
}
__device__ __forceinline__ void ntstore4f(float* p, float4 v) {
    nv_f4 t = {v.x, v.y, v.z, v.w};
    __builtin_nontemporal_store(t, (nv_f4*)p);
}

// bf16 helpers: round-to-nearest-even pack, cheap unpack (hi half is a free AND)
__device__ __forceinline__ unsigned short f2bf(float f) {
    unsigned u = __float_as_uint(f);
    u += 0x7fffu + ((u >> 16) & 1u);
    return (unsigned short)(u >> 16);
}
__device__ __forceinline__ float bflo(unsigned u) { return __uint_as_float(u << 16); }
__device__ __forceinline__ float bfhi(unsigned u) { return __uint_as_float(u & 0xffff0000u); }

// compact bucket entry: (c << 14) | q, q = round(v * 16384), v in [0,1).
// Out-of-range v: quantized-clamped entry + EXACT fp32 residual edge via the
// overflow list -> correct for arbitrary inputs.
__device__ __forceinline__ void put_edge(int r, int c, float v, int pos, int sup,
                                         unsigned* __restrict__ pk, int cap,
                                         int* __restrict__ over_cnt, int4* __restrict__ over) {
    if (pos < cap) {
        float vc = fminf(fmaxf(v, 0.f), 16383.5f / 16384.f);
        int q = (int)fmaf(vc, 16384.f, 0.5f);
        if (q > 16383) q = 16383;
        pk[(size_t)r * cap + pos] = ((unsigned)c << 14) | (unsigned)q;   // cached store
        float resid = v - (float)q * (1.f / 16384.f);   // exact: q/2^14 exact in fp32
        if (fabsf(resid) > 1.2e-4f) {                    // only out-of-range v trips this
            int op = atomicAdd(over_cnt, 1);
            if (op < OVER_MAX) over[op] = make_int4(r, c, __float_as_int(resid), sup);
        }
    } else {
        int op = atomicAdd(over_cnt, 1);
        if (op < OVER_MAX) over[op] = make_int4(r, c, __float_as_int(v), sup);
    }
}

// ================= primary path =================
// prep (fused): sim partials + diff precompute + oa16 conversion +
// XCD-partitioned bucket binning. Streaming accesses use nt hints
// (measured -8us, R10). Bucket/cnt traffic stays cached.
__global__ void prep_bin_kernel(const float* __restrict__ inputs,
                                const float* __restrict__ old_act,
                                const int* __restrict__ fields,
                                const int* __restrict__ sub_rows, const int* __restrict__ sub_cols,
                                const float* __restrict__ sub_vals, int e_sub,
                                const int* __restrict__ sup_rows, const int* __restrict__ sup_cols,
                                const float* __restrict__ sup_vals, int e_sup,
                                int* __restrict__ cnt,            // [2*nrows] + over_cnt at [2*nrows]
                                unsigned* __restrict__ pk_sub, unsigned* __restrict__ pk_sup,
                                int4* __restrict__ over,
                                float* __restrict__ partials, float* __restrict__ diff,
                                unsigned short* __restrict__ oa16,
                                unsigned short* __restrict__ diff16, int n_old4,
                                int mode, int nrows, int n4) {
    int tid = blockIdx.x * blockDim.x + threadIdx.x;
    int stride = gridDim.x * blockDim.x;
    int* over_cnt = cnt + 2 * nrows;

    // sim + diff (float4 in, diff out as f32 or bf16) — all streaming: nt
    float dot = 0.f, nx = 0.f, ny = 0.f;
    for (int i = tid; i < n4; i += stride) {
        int idx = i * 4;
        int b = idx >> 7, d = idx & (DIM - 1);
        float4 x = ntload4f(inputs + idx);
        int f = fields[b];                                  // reused 32x/row: cached
        float4 y = ntload4f(old_act + (size_t)f * DIM + d);
        dot += x.x * y.x + x.y * y.y + x.z * y.z + x.w * y.w;
        nx  += x.x * x.x + x.y * x.y + x.z * x.z + x.w * x.w;
        ny  += y.x * y.x + y.y * y.y + y.z * y.z + y.w * y.w;
        if (mode == 2) {
            ntstore4us(diff16 + idx,
                       make_ushort4(f2bf(x.x - y.x), f2bf(x.y - y.y),
                                    f2bf(x.z - y.z), f2bf(x.w - y.w)));
        } else if (mode == 1) {
            ntstore4f(diff + idx,
                      make_float4(x.x - y.x, x.y - y.y, x.z - y.z, x.w - y.w));
        }
    }

    // old_act -> bf16 copy (mode 2): pure streaming: nt both sides
    if (mode == 2) {
        for (int i = tid; i < n_old4; i += stride) {
            int idx = i * 4;
            float4 y = ntload4f(old_act + idx);
            ntstore4us(oa16 + idx,
                       make_ushort4(f2bf(y.x), f2bf(y.y), f2bf(y.z), f2bf(y.w)));
        }
    }

    // XCD-partitioned binning: group x = blocks with blockIdx&7==x bins rows
    // r&7==x. Edge-array scan is 8x-redundant streaming: nt loads.
    int grp     = blockIdx.x & (NXCD - 1);
    int gblk    = blockIdx.x >> 3;
    int gtid    = gblk * blockDim.x + threadIdx.x;
    int gstride = (gridDim.x >> 3) * blockDim.x;

#define BIN_SCAN(ROWS, COLS, VALS, E, SUP, CBASE, PK, CAP)                              \
    {                                                                                   \
        int e4 = (E) & ~3;                                                              \
        for (int i = gtid * 4; i < e4; i += gstride * 4) {                              \
            int4 rr = ntload4i((ROWS) + i);                                             \
            bool m0 = (rr.x & (NXCD - 1)) == grp;                                       \
            bool m1 = (rr.y & (NXCD - 1)) == grp;                                       \
            bool m2 = (rr.z & (NXCD - 1)) == grp;                                       \
            bool m3 = (rr.w & (NXCD - 1)) == grp;                                       \
            int p0 = 0, p1 = 0, p2 = 0, p3 = 0;                                         \
            int c0 = 0, c1 = 0, c2 = 0, c3 = 0;                                         \
            float v0 = 0.f, v1 = 0.f, v2 = 0.f, v3 = 0.f;                               \
            /* issue phase: loads + atomics, no use of returned positions */            \
            if (m0) { c0 = ntloadi((COLS) + i);     v0 = ntloadf((VALS) + i);     p0 = atomicAdd(&cnt[(CBASE) + rr.x], 1); } \
            if (m1) { c1 = ntloadi((COLS) + i + 1); v1 = ntloadf((VALS) + i + 1); p1 = atomicAdd(&cnt[(CBASE) + rr.y], 1); } \
            if (m2) { c2 = ntloadi((COLS) + i + 2); v2 = ntloadf((VALS) + i + 2); p2 = atomicAdd(&cnt[(CBASE) + rr.z], 1); } \
            if (m3) { c3 = ntloadi((COLS) + i + 3); v3 = ntloadf((VALS) + i + 3); p3 = atomicAdd(&cnt[(CBASE) + rr.w], 1); } \
            /* drain phase: dependent stores (cached, want them in L2) */               \
            if (m0) put_edge(rr.x, c0, v0, p0, (SUP), (PK), (CAP), over_cnt, over);     \
            if (m1) put_edge(rr.y, c1, v1, p1, (SUP), (PK), (CAP), over_cnt, over);     \
            if (m2) put_edge(rr.z, c2, v2, p2, (SUP), (PK), (CAP), over_cnt, over);     \
            if (m3) put_edge(rr.w, c3, v3, p3, (SUP), (PK), (CAP), over_cnt, over);     \
        }                                                                               \
        for (int i = e4 + gtid; i < (E); i += gstride) {                                \
            int r = (ROWS)[i];                                                          \
            if ((r & (NXCD - 1)) == grp) {                                              \
                int c = (COLS)[i]; float v = (VALS)[i];                                 \
                int p = atomicAdd(&cnt[(CBASE) + r], 1);                                \
                put_edge(r, c, v, p, (SUP), (PK), (CAP), over_cnt, over);               \
            }                                                                           \
        }                                                                               \
    }

    BIN_SCAN(sub_rows, sub_cols, sub_vals, e_sub, 0, 0,     pk_sub, SUB_CAP)
    BIN_SCAN(sup_rows, sup_cols, sup_vals, e_sup, 1, nrows, pk_sup, SUP_CAP)
#undef BIN_SCAN

    // block-reduce sim
    for (int off = 32; off > 0; off >>= 1) {
        dot += __shfl_down(dot, off, 64);
        nx  += __shfl_down(nx,  off, 64);
        ny  += __shfl_down(ny,  off, 64);
    }
    __shared__ float s[3][4];
    int lane = threadIdx.x & 63, wv = threadIdx.x >> 6;
    if (lane == 0) { s[0][wv] = dot; s[1][wv] = nx; s[2][wv] = ny; }
    __syncthreads();
    if (threadIdx.x == 0) {
        float D = 0.f, NX = 0.f, NY = 0.f;
        for (int w = 0; w < 4; ++w) { D += s[0][w]; NX += s[1][w]; NY += s[2][w]; }
        partials[blockIdx.x * 3 + 0] = D;
        partials[blockIdx.x * 3 + 1] = NX;
        partials[blockIdx.x * 3 + 2] = NY;
    }
}

// bf16 row accumulate: one wave per row, XCD-affine mapping.
// 16-lane quad gathers: quad q (lanes 16q..16q+15) handles edge j+q; each lane
// loads uint4 = 8 bf16 dims -> a row is 16 requests of 16B, 4 edges per
// wave-step. ALL loads cached (R10: nt bucket reads regressed ~+16us).
__global__ void row_bucket16_kernel(const int* __restrict__ cnt,
                                    const unsigned* __restrict__ pk_sub,
                                    const unsigned* __restrict__ pk_sup,
                                    const unsigned short* __restrict__ diff16,
                                    const unsigned short* __restrict__ oa16,
                                    float* __restrict__ out, int nrows) {
    int wv = threadIdx.x >> 6, lane = threadIdx.x & 63;
    int grp = blockIdx.x & (NXCD - 1);
    int qb  = blockIdx.x >> 3;
    int r   = grp + NXCD * (qb * 4 + wv);
    if (r >= nrows) return;
    const int quad = lane >> 4;        // 0..3 : edge slot
    const int l16  = lane & 15;
    const int d8   = l16 * 8;          // dims [d8 .. d8+7]
    float a0 = 0.f, a1 = 0.f, a2 = 0.f, a3 = 0.f;
    float a4 = 0.f, a5 = 0.f, a6 = 0.f, a7 = 0.f;

#define GATH8(SRC, U)                                                       \
    {                                                                       \
        int   c_ = (int)((U) >> 14);                                        \
        float v_ = (float)((U) & 16383u) * (1.f / 16384.f);                 \
        uint4 g_ = *(const uint4*)((SRC) + ((size_t)c_ << 7) + d8);         \
        a0 += v_ * bflo(g_.x); a1 += v_ * bfhi(g_.x);                       \
        a2 += v_ * bflo(g_.y); a3 += v_ * bfhi(g_.y);                       \
        a4 += v_ * bflo(g_.z); a5 += v_ * bfhi(g_.z);                       \
        a6 += v_ * bflo(g_.w); a7 += v_ * bfhi(g_.w);                       \
    }

    // ---- sub edges (diff16) ----
    {
        int e = cnt[r]; if (e > SUB_CAP) e = SUB_CAP;
        const unsigned* bp = pk_sub + (size_t)r * SUB_CAP;
        int j = 0;
        for (; j + 8 <= e; j += 8) {
            unsigned u0 = bp[j + quad];
            unsigned u1 = bp[j + 4 + quad];
            GATH8(diff16, u0); GATH8(diff16, u1);
        }
        for (; j + 4 <= e; j += 4) {
            unsigned u0 = bp[j + quad];
            GATH8(diff16, u0);
        }
        int rem = e - j;
        if (quad < rem) {
            unsigned u0 = bp[j + quad];
            GATH8(diff16, u0);
        }
    }
    // ---- sup edges (oa16) ----
    {
        int e = cnt[nrows + r]; if (e > SUP_CAP) e = SUP_CAP;
        const unsigned* bp = pk_sup + (size_t)r * SUP_CAP;
        int j = 0;
        for (; j + 16 <= e; j += 16) {
            unsigned u0 = bp[j + quad];
            unsigned u1 = bp[j + 4 + quad];
            unsigned u2 = bp[j + 8 + quad];
            unsigned u3 = bp[j + 12 + quad];
            GATH8(oa16, u0); GATH8(oa16, u1); GATH8(oa16, u2); GATH8(oa16, u3);
        }
        for (; j + 4 <= e; j += 4) {
            unsigned u0 = bp[j + quad];
            GATH8(oa16, u0);
        }
        int rem = e - j;
        if (quad < rem) {
            unsigned u0 = bp[j + quad];
            GATH8(oa16, u0);
        }
    }
#undef GATH8
    // fold the 4 quads
    a0 += __shfl_xor(a0, 16, 64); a0 += __shfl_xor(a0, 32, 64);
    a1 += __shfl_xor(a1, 16, 64); a1 += __shfl_xor(a1, 32, 64);
    a2 += __shfl_xor(a2, 16, 64); a2 += __shfl_xor(a2, 32, 64);
    a3 += __shfl_xor(a3, 16, 64); a3 += __shfl_xor(a3, 32, 64);
    a4 += __shfl_xor(a4, 16, 64); a4 += __shfl_xor(a4, 32, 64);
    a5 += __shfl_xor(a5, 16, 64); a5 += __shfl_xor(a5, 32, 64);
    a6 += __shfl_xor(a6, 16, 64); a6 += __shfl_xor(a6, 32, 64);
    a7 += __shfl_xor(a7, 16, 64); a7 += __shfl_xor(a7, 32, 64);
    if (quad == 0) {
        *(float4*)(out + (size_t)r * DIM + d8)     = make_float4(a0, a1, a2, a3);
        *(float4*)(out + (size_t)r * DIM + d8 + 4) = make_float4(a4, a5, a6, a7);
    }
}

// fp32 row accumulate (fallback tiers, compact-entry decode)
__global__ void row_bucket_kernel(const int* __restrict__ cnt,
                                  const unsigned* __restrict__ pk_sub,
                                  const unsigned* __restrict__ pk_sup,
                                  const float* __restrict__ diff,
                                  const float* __restrict__ inputs, const float* __restrict__ old_act,
                                  const int* __restrict__ fields,
                                  float* __restrict__ out, int nrows, int use_diff) {
    int wv = threadIdx.x >> 6, lane = threadIdx.x & 63;
    int grp = blockIdx.x & (NXCD - 1);
    int q   = blockIdx.x >> 3;
    int r   = grp + NXCD * (q * 4 + wv);
    if (r >= nrows) return;
    const int half = lane >> 5;
    const int l32  = lane & 31;
    const int d4   = l32 * 4;
    float a0 = 0.f, a1 = 0.f, a2 = 0.f, a3 = 0.f;
    {
        int e = cnt[r]; if (e > SUB_CAP) e = SUB_CAP;
        const unsigned* bp = pk_sub + (size_t)r * SUB_CAP;
        int j = 0;
        for (; j + 2 <= e; j += 2) {
            unsigned u = bp[j + half];
            int c = (int)(u >> 14);
            float v = (float)(u & 16383u) * (1.f / 16384.f);
            if (use_diff) {
                float4 g = *(const float4*)(diff + (size_t)c * DIM + d4);
                a0 += v * g.x; a1 += v * g.y; a2 += v * g.z; a3 += v * g.w;
            } else {
                int f = fields[c];
                float4 x = *(const float4*)(inputs  + (size_t)c * DIM + d4);
                float4 y = *(const float4*)(old_act + (size_t)f * DIM + d4);
                a0 += v * (x.x - y.x); a1 += v * (x.y - y.y);
                a2 += v * (x.z - y.z); a3 += v * (x.w - y.w);
            }
        }
        if (j < e && half == 0) {
            unsigned u = bp[j];
            int c = (int)(u >> 14);
            float v = (float)(u & 16383u) * (1.f / 16384.f);
            if (use_diff) {
                float4 g = *(const float4*)(diff + (size_t)c * DIM + d4);
                a0 += v * g.x; a1 += v * g.y; a2 += v * g.z; a3 += v * g.w;
            } else {
                int f = fields[c];
                float4 x = *(const float4*)(inputs  + (size_t)c * DIM + d4);
                float4 y = *(const float4*)(old_act + (size_t)f * DIM + d4);
                a0 += v * (x.x - y.x); a1 += v * (x.y - y.y);
                a2 += v * (x.z - y.z); a3 += v * (x.w - y.w);
            }
        }
    }
    {
        int e = cnt[nrows + r]; if (e > SUP_CAP) e = SUP_CAP;
        const unsigned* bp = pk_sup + (size_t)r * SUP_CAP;
        int j = 0;
        for (; j + 2 <= e; j += 2) {
            unsigned u = bp[j + half];
            int c = (int)(u >> 14);
            float v = (float)(u & 16383u) * (1.f / 16384.f);
            float4 g = *(const float4*)(old_act + (size_t)c * DIM + d4);
            a0 += v * g.x; a1 += v * g.y; a2 += v * g.z; a3 += v * g.w;
        }
        if (j < e && half == 0) {
            unsigned u = bp[j];
            int c = (int)(u >> 14);
            float v = (float)(u & 16383u) * (1.f / 16384.f);
            float4 g = *(const float4*)(old_act + (size_t)c * DIM + d4);
            a0 += v * g.x; a1 += v * g.y; a2 += v * g.z; a3 += v * g.w;
        }
    }
    float b0 = __shfl(a0, lane ^ 32, 64);
    float b1 = __shfl(a1, lane ^ 32, 64);
    float b2 = __shfl(a2, lane ^ 32, 64);
    float b3 = __shfl(a3, lane ^ 32, 64);
    if (half == 0) {
        *(float4*)(out + (size_t)r * DIM + d4) = make_float4(a0 + b0, a1 + b1, a2 + b2, a3 + b3);
    }
}

// tail: sim finalize + overflow/residual edges (mode selects gather source)
__global__ void tail_kernel(const float* __restrict__ partials, int np,
                            const int* __restrict__ cnt, const int4* __restrict__ over,
                            const float* __restrict__ diff,
                            const float* __restrict__ inputs, const float* __restrict__ old_act,
                            const int* __restrict__ fields,
                            const unsigned short* __restrict__ oa16,
                            const unsigned short* __restrict__ diff16,
                            float* __restrict__ out, int nrows, int n, int mode) {
    if (blockIdx.x == 0 && threadIdx.x < 64) {
        double dot = 0.0, nx = 0.0, ny = 0.0;
        for (int i = threadIdx.x; i < np; i += 64) {
            dot += (double)partials[i * 3 + 0];
            nx  += (double)partials[i * 3 + 1];
            ny  += (double)partials[i * 3 + 2];
        }
        for (int off = 32; off > 0; off >>= 1) {
            dot += __shfl_down(dot, off, 64);
            nx  += __shfl_down(nx,  off, 64);
            ny  += __shfl_down(ny,  off, 64);
        }
        if (threadIdx.x == 0)
            out[n] = (float)(dot / (sqrt(nx) * sqrt(ny)));
    }
    int no = cnt[2 * nrows]; if (no > OVER_MAX) no = OVER_MAX;
    int tid = blockIdx.x * blockDim.x + threadIdx.x;
    int stride = gridDim.x * blockDim.x;
    for (int i = tid; i < no; i += stride) {
        int4 t = over[i];
        int r = t.x, c = t.y, sup = t.w;
        float v = __int_as_float(t.z);
        for (int d = 0; d < DIM; ++d) {
            float term;
            if (mode == 2) {
                term = sup ? bflo((unsigned)oa16[(size_t)c * DIM + d])
                           : bflo((unsigned)diff16[(size_t)c * DIM + d]);
            } else if (sup) term = old_act[(size_t)c * DIM + d];
            else if (mode == 1) term = diff[(size_t)c * DIM + d];
            else term = inputs[(size_t)c * DIM + d] - old_act[(size_t)fields[c] * DIM + d];
            atomicAdd(&out[(size_t)r * DIM + d], v * term);
        }
    }
}

// ================= fallback: round-4 scan pipeline (proven) =================
__global__ void prep4_kernel(const float* __restrict__ inputs, const float* __restrict__ old_act,
                             const int* __restrict__ fields,
                             const int* __restrict__ sub_rows, int e_sub,
                             const int* __restrict__ sup_rows, int e_sup,
                             int* __restrict__ cnt, float* __restrict__ partials,
                             int nrows, int n2) {
    int tid = blockIdx.x * blockDim.x + threadIdx.x;
    int stride = gridDim.x * blockDim.x;
    float dot = 0.f, nx = 0.f, ny = 0.f;
    for (int i = tid; i < n2; i += stride) {
        int idx = i * 2;
        int b = idx >> 7, d = idx & (DIM - 1);
        float2 x = *(const float2*)(inputs + idx);
        int f = fields[b];
        float2 y = *(const float2*)(old_act + (size_t)f * DIM + d);
        dot += x.x * y.x + x.y * y.y;
        nx  += x.x * x.x + x.y * x.y;
        ny  += y.x * y.x + y.y * y.y;
    }
    int e_tot = e_sub + e_sup;
    for (int i = tid; i < e_tot; i += stride) {
        int r = (i < e_sub) ? sub_rows[i] : (nrows + sup_rows[i - e_sub]);
        atomicAdd(&cnt[r], 1);
    }
    for (int off = 32; off > 0; off >>= 1) {
        dot += __shfl_down(dot, off, 64);
        nx  += __shfl_down(nx,  off, 64);
        ny  += __shfl_down(ny,  off, 64);
    }
    __shared__ float s[3][4];
    int lane = threadIdx.x & 63, wv = threadIdx.x >> 6;
    if (lane == 0) { s[0][wv] = dot; s[1][wv] = nx; s[2][wv] = ny; }
    __syncthreads();
    if (threadIdx.x == 0) {
        float D = 0.f, NX = 0.f, NY = 0.f;
        for (int w = 0; w < 4; ++w) { D += s[0][w]; NX += s[1][w]; NY += s[2][w]; }
        partials[blockIdx.x * 3 + 0] = D;
        partials[blockIdx.x * 3 + 1] = NX;
        partials[blockIdx.x * 3 + 2] = NY;
    }
}

__global__ void finalize4_kernel(const float* __restrict__ partials, int np,
                                 float* __restrict__ out_sim) {
    double dot = 0.0, nx = 0.0, ny = 0.0;
    for (int i = threadIdx.x; i < np; i += 64) {
        dot += (double)partials[i * 3 + 0];
        nx  += (double)partials[i * 3 + 1];
        ny  += (double)partials[i * 3 + 2];
    }
    for (int off = 32; off > 0; off >>= 1) {
        dot += __shfl_down(dot, off, 64);
        nx  += __shfl_down(nx,  off, 64);
        ny  += __shfl_down(ny,  off, 64);
    }
    if (threadIdx.x == 0)
        *out_sim = (float)(dot / (sqrt(nx) * sqrt(ny)));
}

__global__ void scanA_kernel(const int* __restrict__ cnt, int* __restrict__ tmp,
                             int* __restrict__ bsum, int m) {
    __shared__ int s[256];
    int i = blockIdx.x * 256 + threadIdx.x;
    int v = (i < m) ? cnt[i] : 0;
    s[threadIdx.x] = v;
    __syncthreads();
    for (int d = 1; d < 256; d <<= 1) {
        int t = (threadIdx.x >= (unsigned)d) ? s[threadIdx.x - d] : 0;
        __syncthreads();
        s[threadIdx.x] += t;
        __syncthreads();
    }
    if (i < m) tmp[i] = s[threadIdx.x] - v;
    if (threadIdx.x == 255) bsum[blockIdx.x] = s[255];
}

__global__ void scanB_kernel(int* __restrict__ bsum, int* __restrict__ boff, int nb) {
    __shared__ int s[512];
    int v = (threadIdx.x < nb) ? bsum[threadIdx.x] : 0;
    s[threadIdx.x] = v;
    __syncthreads();
    for (int d = 1; d < 512; d <<= 1) {
        int t = (threadIdx.x >= (unsigned)d) ? s[threadIdx.x - d] : 0;
        __syncthreads();
        s[threadIdx.x] += t;
        __syncthreads();
    }
    if (threadIdx.x < nb) boff[threadIdx.x] = s[threadIdx.x] - v;
}

__global__ void scanC_kernel(const int* tmp, const int* __restrict__ boff,
                             int* __restrict__ off, int* cur, int m, int e_tot) {
    int i = blockIdx.x * 256 + threadIdx.x;
    if (i < m) {
        int o = tmp[i] + boff[i >> 8];
        off[i] = o;
        cur[i] = o;
    }
    if (i == 0) off[m] = e_tot;
}

__global__ void scatter4_kernel(const int* __restrict__ sub_rows, const int* __restrict__ sub_cols,
                                const float* __restrict__ sub_vals, int e_sub,
                                const int* __restrict__ sup_rows, const int* __restrict__ sup_cols,
                                const float* __restrict__ sup_vals, int e_sup,
                                int* __restrict__ cur, int2* __restrict__ pk, int nrows) {
    int i = blockIdx.x * blockDim.x + threadIdx.x;
    int e_tot = e_sub + e_sup;
    if (i >= e_tot) return;
    int r, c; float v;
    if (i < e_sub) { r = sub_rows[i]; c = sub_cols[i]; v = sub_vals[i]; }
    else { int k = i - e_sub; r = nrows + sup_rows[k]; c = sup_cols[k]; v = sup_vals[k]; }
    int pos = atomicAdd(&cur[r], 1);
    pk[pos] = make_int2(c, __float_as_int(v));
}

__global__ void row4_kernel(const int* __restrict__ off, const int2* __restrict__ pk,
                            const float* __restrict__ inputs, const float* __restrict__ old_act,
                            const int* __restrict__ fields, float* __restrict__ out, int nrows) {
    int wv = threadIdx.x >> 6, lane = threadIdx.x & 63;
    int r = blockIdx.x * (blockDim.x >> 6) + wv;
    if (r >= nrows) return;
    int d0 = lane * 2;
    float a0 = 0.f, a1 = 0.f;
    int b = off[r], e = off[r + 1];
    for (int j = b; j < e; ++j) {
        int2 p = pk[j];
        int c = p.x; float v = __int_as_float(p.y);
        int f = fields[c];
        float2 x = *(const float2*)(inputs  + (size_t)c * DIM + d0);
        float2 y = *(const float2*)(old_act + (size_t)f * DIM + d0);
        a0 += v * (x.x - y.x);
        a1 += v * (x.y - y.y);
    }
    b = off[nrows + r]; e = off[nrows + r + 1];
    for (int j = b; j < e; ++j) {
        int2 p = pk[j];
        int c = p.x; float v = __int_as_float(p.y);
        float2 y = *(const float2*)(old_act + (size_t)c * DIM + d0);
        a0 += v * y.x;
        a1 += v * y.y;
    }
    *(float2*)(out + (size_t)r * DIM + d0) = make_float2(a0, a1);
}

extern "C" void kernel_launch(void* const* d_in, const int* in_sizes, int n_in,
                              void* d_out, int out_size, void* d_ws, size_t ws_size,
                              hipStream_t stream) {
    const float* inputs   = (const float*)d_in[0];
    const float* old_act  = (const float*)d_in[1];
    const int*   fields   = (const int*)d_in[2];
    const int*   sub_rows = (const int*)d_in[3];
    const int*   sub_cols = (const int*)d_in[4];
    const float* sub_vals = (const float*)d_in[5];
    const int*   sup_rows = (const int*)d_in[6];
    const int*   sup_cols = (const int*)d_in[7];
    const float* sup_vals = (const float*)d_in[8];

    const int n     = in_sizes[0];     // BATCH * DIM
    const int nrows = n / DIM;         // BATCH
    const int n_old = in_sizes[1];     // N_DATA * DIM
    const int e_sub = in_sizes[3];
    const int e_sup = in_sizes[6];
    const int e_tot = e_sub + e_sup;

    float* out = (float*)d_out;
    char*  ws  = (char*)d_ws;

    // ---- workspace layout (compact 4B bucket entries) ----
    size_t off_part = 0;                                                // f32[PREP_GRID*3]
    size_t off_cnt  = (PREP_GRID * 3 * 4 + 63) & ~(size_t)63;           // int[2*nrows+1]
    size_t off_over = (off_cnt + (size_t)(2 * nrows + 1) * 4 + 15) & ~(size_t)15;  // int4[OVER_MAX]
    size_t off_psub = off_over + (size_t)OVER_MAX * 16;                 // u32[nrows*SUB_CAP]
    size_t off_psup = off_psub + (size_t)nrows * SUB_CAP * 4;           // u32[nrows*SUP_CAP]
    size_t off_aux  = off_psup + (size_t)nrows * SUP_CAP * 4;           // (oa16+diff16) or f32 diff
    size_t need_base = off_aux;
    size_t need_diff = off_aux + (size_t)n * 4;
    size_t off_oa16 = off_aux;                                          // u16[n_old]
    size_t off_d16  = (off_oa16 + (size_t)n_old * 2 + 15) & ~(size_t)15; // u16[n]
    size_t need16   = off_d16 + (size_t)n * 2;

    int nblk = NXCD * ((((nrows + NXCD - 1) / NXCD) + 3) / 4);

    if (ws_size >= need_base) {
        float*    partials = (float*)(ws + off_part);
        int*      cnt      = (int*)(ws + off_cnt);
        int4*     over     = (int4*)(ws + off_over);
        unsigned* pk_sub   = (unsigned*)(ws + off_psub);
        unsigned* pk_sup   = (unsigned*)(ws + off_psup);
        float*    diff     = (float*)(ws + off_aux);
        unsigned short* oa16   = (unsigned short*)(ws + off_oa16);
        unsigned short* diff16 = (unsigned short*)(ws + off_d16);
        int mode;
        if (ws_size >= need16)         mode = 2;   // bf16 gathers
        else if (ws_size >= need_diff) mode = 1;   // f32 diff
        else                           mode = 0;   // no diff buffer

        hipMemsetAsync(cnt, 0, (size_t)(2 * nrows + 1) * 4, stream);

        prep_bin_kernel<<<PREP_GRID, TPB, 0, stream>>>(
            inputs, old_act, fields,
            sub_rows, sub_cols, sub_vals, e_sub,
            sup_rows, sup_cols, sup_vals, e_sup,
            cnt, pk_sub, pk_sup, over, partials, diff,
            oa16, diff16, n_old / 4, mode, nrows, n / 4);

        if (mode == 2) {
            row_bucket16_kernel<<<nblk, TPB, 0, stream>>>(
                cnt, pk_sub, pk_sup, diff16, oa16, out, nrows);
        } else {
            row_bucket_kernel<<<nblk, TPB, 0, stream>>>(
                cnt, pk_sub, pk_sup, diff, inputs, old_act, fields, out, nrows, mode);
        }

        tail_kernel<<<32, TPB, 0, stream>>>(
            partials, PREP_GRID, cnt, over, diff, inputs, old_act, fields,
            oa16, diff16, out, nrows, n, mode);
        return;
    }

    // ---- fallback: round-4 scan pipeline ----
    const int m     = 2 * nrows;
    const int nblkA = (m + 255) / 256;
    size_t f_part = 0;
    size_t f_cnt  = (2048 * 3 * 4 + 63) & ~(size_t)63;
    size_t f_tmp  = f_cnt + (size_t)m * 4;
    size_t f_offs = f_tmp + (size_t)m * 4;
    size_t f_bsum = f_offs + (size_t)(m + 1) * 4;
    size_t f_boff = f_bsum + 4096;
    size_t f_pk   = (f_boff + 4096 + 7) & ~(size_t)7;
    size_t f_need = f_pk + (size_t)e_tot * 8;

    float* partials = (float*)(ws + f_part);
    int*   cnt      = (int*)(ws + f_cnt);
    int*   tmp      = (int*)(ws + f_tmp);
    int*   offs     = (int*)(ws + f_offs);
    int*   bsum     = (int*)(ws + f_bsum);
    int*   boff     = (int*)(ws + f_boff);
    int2*  pk       = (int2*)(ws + f_pk);

    if (ws_size >= f_need && nblkA <= 512) {
        hipMemsetAsync(cnt, 0, (size_t)m * 4, stream);
        prep4_kernel<<<2048, 256, 0, stream>>>(inputs, old_act, fields,
                                               sub_rows, e_sub, sup_rows, e_sup,
                                               cnt, partials, nrows, n / 2);
        scanA_kernel<<<nblkA, 256, 0, stream>>>(cnt, tmp, bsum, m);
        scanB_kernel<<<1, 512, 0, stream>>>(bsum, boff, nblkA);
        scanC_kernel<<<nblkA, 256, 0, stream>>>(tmp, boff, offs, tmp, m, e_tot);
        scatter4_kernel<<<(e_tot + 255) / 256, 256, 0, stream>>>(
            sub_rows, sub_cols, sub_vals, e_sub,
            sup_rows, sup_cols, sup_vals, e_sup, tmp, pk, nrows);
        row4_kernel<<<(nrows + 3) / 4, 256, 0, stream>>>(offs, pk, inputs, old_act,
                                                         fields, out, nrows);
        finalize4_kernel<<<1, 64, 0, stream>>>(partials, 2048, out + n);
    }
}